// Round 1
// baseline (12236.758 us; speedup 1.0000x reference)
//
#include <hip/hip_runtime.h>
#include <math.h>

#define DIM 768
#define NHEAD 12
#define DHEAD 64
#define FFDIM 3072

__device__ __forceinline__ float gelu_f(float x) {
    float x3 = x * x * x;
    return 0.5f * x * (1.0f + tanhf(0.7978845608028654f * (x + 0.044715f * x3)));
}

// ---------------- generic fp32 GEMM: C[M,N] = A[M,K] @ B[K,N], epilogue ----------------
// epi: 0 = none, 1 = gelu, 2 = tanh(x + bias[col])
__global__ __launch_bounds__(256) void gemm_kernel(const float* __restrict__ A,
    const float* __restrict__ B, float* __restrict__ C,
    int M, int N, int Kd, int epi, const float* __restrict__ bias)
{
    __shared__ float As[16][64];   // [k][m]
    __shared__ float Bs[16][64];   // [k][n]
    int tid = threadIdx.x;
    int tx = tid & 15, ty = tid >> 4;
    int row0 = blockIdx.y << 6, col0 = blockIdx.x << 6;
    int ar = tid >> 2, ak = (tid & 3) << 2;
    int bc = tid & 63, bk0 = tid >> 6;
    const float* Ap = A + (size_t)(row0 + ar) * Kd + ak;
    const float* Bp = B + (size_t)bk0 * N + col0 + bc;
    bool aval = (row0 + ar) < M;
    float acc[4][4];
#pragma unroll
    for (int i = 0; i < 4; i++)
#pragma unroll
        for (int j = 0; j < 4; j++) acc[i][j] = 0.f;

    for (int k0 = 0; k0 < Kd; k0 += 16) {
        float4 a4 = make_float4(0.f, 0.f, 0.f, 0.f);
        if (aval) a4 = *(const float4*)(Ap + k0);
        As[ak + 0][ar] = a4.x; As[ak + 1][ar] = a4.y;
        As[ak + 2][ar] = a4.z; As[ak + 3][ar] = a4.w;
#pragma unroll
        for (int i = 0; i < 4; i++)
            Bs[bk0 + 4 * i][bc] = Bp[(size_t)(k0 + 4 * i) * N];
        __syncthreads();
#pragma unroll
        for (int kk = 0; kk < 16; kk++) {
            float4 av = *(const float4*)&As[kk][ty << 2];
            float4 bv = *(const float4*)&Bs[kk][tx << 2];
            float aa[4] = {av.x, av.y, av.z, av.w};
            float bb[4] = {bv.x, bv.y, bv.z, bv.w};
#pragma unroll
            for (int i = 0; i < 4; i++)
#pragma unroll
                for (int j = 0; j < 4; j++)
                    acc[i][j] = fmaf(aa[i], bb[j], acc[i][j]);
        }
        __syncthreads();
    }
#pragma unroll
    for (int i = 0; i < 4; i++) {
        int r = row0 + (ty << 2) + i;
        if (r >= M) continue;
        float o0, o1, o2, o3;
        float v[4];
#pragma unroll
        for (int j = 0; j < 4; j++) {
            float x = acc[i][j];
            if (epi == 1) x = gelu_f(x);
            else if (epi == 2) x = tanhf(x + bias[col0 + (tx << 2) + j]);
            v[j] = x;
        }
        o0 = v[0]; o1 = v[1]; o2 = v[2]; o3 = v[3];
        *(float4*)(C + (size_t)r * N + col0 + (tx << 2)) = make_float4(o0, o1, o2, o3);
    }
}

// ---------------- prefix build + pooled attention mask ----------------
__global__ __launch_bounds__(256) void build_prefix_kernel(const int* __restrict__ sub,
    const float* __restrict__ mask, const float* __restrict__ amask,
    float* __restrict__ P, float* __restrict__ attn_out, int seq0)
{
    __shared__ float pref[64 * 64];
    int gl = blockIdx.x;
    int g = seq0 + gl;
    int tid = threadIdx.x;
    for (int t = tid; t < 4096; t += 256) pref[t] = 0.f;
    __syncthreads();
    if (tid < 64) {
        int r = sub[((size_t)g * 64 + tid) * 2 + 0];
        int c = sub[((size_t)g * 64 + tid) * 2 + 1];
        pref[(r << 6) + c] = 1.0f;   // duplicate writes of same value: benign
    }
    __syncthreads();
    float m = mask[g];
    int lane = tid & 63, w = tid >> 6;
    for (int s = (w << 4); s < (w << 4) + 16; s++) {
        float v = pref[(s << 6) + lane] * m;
        float rs = v;
#pragma unroll
        for (int o = 32; o; o >>= 1) rs += __shfl_down(rs, o);
        rs = __shfl(rs, 0);
        float nv = v / fmaxf(rs, 1e-12f);
        P[(((size_t)gl << 6) + s) * 64 + lane] = nv;
        float av = nv * amask[((size_t)g << 6) + lane];
#pragma unroll
        for (int o = 32; o; o >>= 1) av += __shfl_down(av, o);
        if (lane == 0) attn_out[((size_t)g << 6) + s] = av;
    }
}

// ---------------- subword->token embedding pooling: X[row] = prefix_row @ emb[tok] --------
__global__ __launch_bounds__(256) void emb_pool_kernel(const float* __restrict__ P,
    const int* __restrict__ enc, const float* __restrict__ emb,
    float* __restrict__ X, int seq0)
{
    int s = blockIdx.x & 63;
    int gl = blockIdx.x >> 6;
    int g = seq0 + gl;
    int tid = threadIdx.x;
    __shared__ float pw[64];
    __shared__ int tk[64];
    if (tid < 64) {
        pw[tid] = P[(((size_t)gl << 6) + s) * 64 + tid];
        tk[tid] = enc[((size_t)g << 6) + tid];
    }
    __syncthreads();
    float a0 = 0.f, a1 = 0.f, a2 = 0.f;
    for (int t = 0; t < 64; t++) {
        float w = pw[t];
        if (w != 0.f) {
            const float* er = emb + (size_t)tk[t] * DIM;
            a0 = fmaf(w, er[tid], a0);
            a1 = fmaf(w, er[tid + 256], a1);
            a2 = fmaf(w, er[tid + 512], a2);
        }
    }
    size_t ro = (((size_t)gl << 6) + s) * DIM;
    X[ro + tid] = a0; X[ro + tid + 256] = a1; X[ro + tid + 512] = a2;
}

// ---------------- attention scores + softmax (per g,h,i) ----------------
__global__ __launch_bounds__(256) void attn_scores_kernel(const float* __restrict__ Q,
    const float* __restrict__ Km, const float* __restrict__ mask,
    float* __restrict__ P, int S)
{
    __shared__ float qs[64];
    __shared__ float ps[400];
    __shared__ float red[256];
    int i = blockIdx.x % S;
    int h = (blockIdx.x / S) % NHEAD;
    int g = blockIdx.x / (S * NHEAD);
    int tid = threadIdx.x;
    if (tid < 64) qs[tid] = Q[((size_t)g * S + i) * DIM + h * DHEAD + tid];
    __syncthreads();
    for (int j = tid; j < S; j += 256) {
        const float4* kr = (const float4*)(Km + ((size_t)g * S + j) * DIM + h * DHEAD);
        float d = 0.f;
#pragma unroll
        for (int t = 0; t < 16; t++) {
            float4 k4 = kr[t];
            d = fmaf(qs[4 * t + 0], k4.x, d);
            d = fmaf(qs[4 * t + 1], k4.y, d);
            d = fmaf(qs[4 * t + 2], k4.z, d);
            d = fmaf(qs[4 * t + 3], k4.w, d);
        }
        float mm = mask[(size_t)g * S + j];
        ps[j] = d * 0.125f + (mm > 0.f ? 0.f : -1e9f);
    }
    __syncthreads();
    float lm = -INFINITY;
    for (int j = tid; j < S; j += 256) lm = fmaxf(lm, ps[j]);
    red[tid] = lm; __syncthreads();
    for (int o = 128; o; o >>= 1) { if (tid < o) red[tid] = fmaxf(red[tid], red[tid + o]); __syncthreads(); }
    float mx = red[0];
    __syncthreads();
    float ls = 0.f;
    for (int j = tid; j < S; j += 256) { float e = expf(ps[j] - mx); ps[j] = e; ls += e; }
    red[tid] = ls; __syncthreads();
    for (int o = 128; o; o >>= 1) { if (tid < o) red[tid] += red[tid + o]; __syncthreads(); }
    float inv = 1.0f / red[0];
    float* prow = P + ((size_t)(g * NHEAD + h) * S + i) * S;
    for (int j = tid; j < S; j += 256) prow[j] = ps[j] * inv;
}

// ---------------- attention output: O = P @ V (per g,h, 4 rows/block) ----------------
__global__ void attn_av_kernel(const float* __restrict__ P, const float* __restrict__ V,
    float* __restrict__ O, int S)
{
    int d = threadIdx.x;        // 0..63
    int isub = threadIdx.y;     // 0..3
    int nblk = S >> 2;
    int ib = blockIdx.x % nblk;
    int h = (blockIdx.x / nblk) % NHEAD;
    int g = blockIdx.x / (nblk * NHEAD);
    int i = (ib << 2) + isub;
    const float* pr = P + ((size_t)(g * NHEAD + h) * S + i) * S;
    const float* vb = V + (size_t)g * S * DIM + h * DHEAD + d;
    float acc = 0.f;
    for (int j = 0; j < S; j++) acc = fmaf(pr[j], vb[(size_t)j * DIM], acc);
    O[((size_t)g * S + i) * DIM + h * DHEAD + d] = acc;
}

// ---------------- h = LayerNorm(X + Y), no affine, eps 1e-12 ----------------
__global__ __launch_bounds__(256) void add_ln_kernel(const float* __restrict__ X,
    const float* __restrict__ Y, float* __restrict__ Out)
{
    int r = blockIdx.x, tid = threadIdx.x;
    size_t base = (size_t)r * DIM;
    float v0 = X[base + tid] + Y[base + tid];
    float v1 = X[base + tid + 256] + Y[base + tid + 256];
    float v2 = X[base + tid + 512] + Y[base + tid + 512];
    __shared__ float red[256];
    red[tid] = v0 + v1 + v2; __syncthreads();
    for (int o = 128; o; o >>= 1) { if (tid < o) red[tid] += red[tid + o]; __syncthreads(); }
    float mu = red[0] * (1.f / 768.f);
    __syncthreads();
    float d0 = v0 - mu, d1 = v1 - mu, d2 = v2 - mu;
    red[tid] = d0 * d0 + d1 * d1 + d2 * d2; __syncthreads();
    for (int o = 128; o; o >>= 1) { if (tid < o) red[tid] += red[tid + o]; __syncthreads(); }
    float rstd = rsqrtf(red[0] * (1.f / 768.f) + 1e-12f);
    Out[base + tid] = d0 * rstd;
    Out[base + tid + 256] = d1 * rstd;
    Out[base + tid + 512] = d2 * rstd;
}

__global__ void cls_copy_kernel(const float* __restrict__ H, float* __restrict__ cls, int S) {
    int g = blockIdx.x, tid = threadIdx.x;
    size_t src = (size_t)g * S * DIM;
    cls[(size_t)g * DIM + tid]       = H[src + tid];
    cls[(size_t)g * DIM + tid + 256] = H[src + tid + 256];
    cls[(size_t)g * DIM + tid + 512] = H[src + tid + 512];
}

// ---------------- user attention pooling over 50 history CLS vectors ----------------
__global__ __launch_bounds__(256) void user_pool_kernel(const float* __restrict__ cls,
    const float* __restrict__ qU, float* __restrict__ user0)
{
    int b = blockIdx.x, tid = threadIdx.x;
    __shared__ float red[256];
    __shared__ float wv[64];
    const float scale = 0.03608439182435161f;   // 1/sqrt(768)
    for (int n = 0; n < 50; n++) {
        const float* cr = cls + ((size_t)(b * 50 + n)) * DIM;
        float d = 0.f;
        for (int t = tid; t < DIM; t += 256) d = fmaf(cr[t], qU[t], d);
        red[tid] = d; __syncthreads();
        for (int o = 128; o; o >>= 1) { if (tid < o) red[tid] += red[tid + o]; __syncthreads(); }
        if (tid == 0) wv[n] = red[0] * scale;
        __syncthreads();
    }
    if (tid == 0) {
        float mx = -INFINITY;
        for (int n = 0; n < 50; n++) mx = fmaxf(mx, wv[n]);
        float s = 0.f;
        for (int n = 0; n < 50; n++) { float e = expf(wv[n] - mx); wv[n] = e; s += e; }
        float inv = 1.f / s;
        for (int n = 0; n < 50; n++) wv[n] *= inv;
    }
    __syncthreads();
    for (int d = tid; d < DIM; d += 256) {
        float a = 0.f;
        for (int n = 0; n < 50; n++) a = fmaf(wv[n], cls[((size_t)(b * 50 + n)) * DIM + d], a);
        user0[(size_t)b * DIM + d] = a;
    }
}

// ---------------- personalized-term scores + stable top-8 ----------------
__global__ __launch_bounds__(256) void topk_kernel(const float* __restrict__ hid,
    const float* __restrict__ user0, const float* __restrict__ attn,
    float* __restrict__ kid_f, int* __restrict__ kid_i, float* __restrict__ ps_mask)
{
    int bn = blockIdx.x;            // b*50 + n
    int b = bn / 50;
    int tid = threadIdx.x, lane = tid & 63, w = tid >> 6;
    __shared__ float sc[64];
    const float* u = user0 + (size_t)b * DIM;
    const float scale = 0.03608439182435161f;
    for (int s = w; s < 64; s += 4) {
        const float* hr = hid + ((size_t)bn * 64 + s) * DIM;
        float d = 0.f;
        for (int t = lane; t < DIM; t += 64) d = fmaf(hr[t], u[t], d);
#pragma unroll
        for (int o = 32; o; o >>= 1) d += __shfl_down(d, o);
        if (lane == 0) {
            float a = attn[(size_t)bn * 64 + s];
            sc[s] = (a > 0.f) ? d * scale : -1e9f;
        }
    }
    __syncthreads();
    if (tid == 0) {
        unsigned long long used = 0ull;
        for (int k = 0; k < 8; k++) {
            float best = -INFINITY; int bi = 0;
            for (int s = 0; s < 64; s++) {
                if ((used >> s) & 1ull) continue;
                if (sc[s] > best) { best = sc[s]; bi = s; }   // strict > : ties pick lowest index (jax top_k)
            }
            used |= (1ull << bi);
            kid_i[bn * 8 + k] = bi;
            kid_f[bn * 8 + k] = (float)bi;
            ps_mask[bn * 8 + k] = attn[(size_t)bn * 64 + bi];
        }
    }
}

__global__ void gather_kernel(const float* __restrict__ hid, const int* __restrict__ kid_i,
    float* __restrict__ X)
{
    int r = blockIdx.x, tid = threadIdx.x;  // r = b*400 + n*8 + k = bn*8 + k
    int s = kid_i[r];
    int bn = r >> 3;
    const float* src = hid + ((size_t)bn * 64 + s) * DIM;
    float* dst = X + (size_t)r * DIM;
    dst[tid] = src[tid];
    dst[tid + 256] = src[tid + 256];
    dst[tid + 512] = src[tid + 512];
}

// ---------------- final score + log_softmax over 5 candidates ----------------
__global__ __launch_bounds__(256) void final_kernel(const float* __restrict__ cdd_repr,
    const float* __restrict__ user_repr, float* __restrict__ out)
{
    int b = blockIdx.x, tid = threadIdx.x;
    __shared__ float red[256];
    __shared__ float sc[5];
    const float scale = 0.03608439182435161f;
    for (int c = 0; c < 5; c++) {
        const float* cr = cdd_repr + ((size_t)(b * 5 + c)) * DIM;
        const float* ur = user_repr + (size_t)b * DIM;
        float d = 0.f;
        for (int t = tid; t < DIM; t += 256) d = fmaf(cr[t], ur[t], d);
        red[tid] = d; __syncthreads();
        for (int o = 128; o; o >>= 1) { if (tid < o) red[tid] += red[tid + o]; __syncthreads(); }
        if (tid == 0) sc[c] = red[0] * scale;
        __syncthreads();
    }
    if (tid == 0) {
        float mx = -INFINITY;
        for (int c = 0; c < 5; c++) mx = fmaxf(mx, sc[c]);
        float s = 0.f;
        for (int c = 0; c < 5; c++) s += expf(sc[c] - mx);
        float lse = logf(s) + mx;
        for (int c = 0; c < 5; c++) out[b * 5 + c] = sc[c] - lse;
    }
}

extern "C" void kernel_launch(void* const* d_in, const int* in_sizes, int n_in,
                              void* d_out, int out_size, void* d_ws, size_t ws_size,
                              hipStream_t stream)
{
    (void)in_sizes; (void)n_in; (void)out_size; (void)ws_size;
    const int*   cdd_sub   = (const int*)d_in[0];
    const int*   his_sub   = (const int*)d_in[1];
    const int*   cdd_enc   = (const int*)d_in[2];
    const int*   his_enc   = (const int*)d_in[3];
    const float* cdd_mask  = (const float*)d_in[4];
    const float* his_mask  = (const float*)d_in[5];
    const float* cdd_amask = (const float*)d_in[6];
    const float* his_amask = (const float*)d_in[7];
    const float* emb = (const float*)d_in[8];
    const float* bWq = (const float*)d_in[9],  *bWk = (const float*)d_in[10], *bWv = (const float*)d_in[11];
    const float* bWo = (const float*)d_in[12], *bW1 = (const float*)d_in[13], *bW2 = (const float*)d_in[14];
    const float* eWq = (const float*)d_in[15], *eWk = (const float*)d_in[16], *eWv = (const float*)d_in[17];
    const float* eWo = (const float*)d_in[18], *eW1 = (const float*)d_in[19], *eW2 = (const float*)d_in[20];
    const float* qU = (const float*)d_in[21];
    const float* pW = (const float*)d_in[22];
    const float* pb = (const float*)d_in[23];
    float* out = (float*)d_out;

    // ---- workspace carve-up (floats). total ~50.43M floats ~= 202 MB ----
    float* ws = (float*)d_ws;
    size_t off = 0;
    auto alloc = [&](size_t n) { float* p = ws + off; off += n; return p; };
    const size_t AR = (size_t)3200 * 768;
    float* Xa = alloc(AR); float* Qa = alloc(AR); float* Ka = alloc(AR); float* Va = alloc(AR);
    float* Oa = alloc(AR); float* Ha = alloc(AR);
    float* SF = alloc((size_t)15360000);           // scores (user 8*12*400*400) / FFN (3200*3072) shared
    float* Pa = alloc((size_t)50 * 64 * 64);
    float* hisH = alloc((size_t)400 * 64 * 768);
    float* hisC = alloc((size_t)400 * 768);
    float* cddC = alloc((size_t)64 * 768);
    float* userC = alloc((size_t)8 * 768);
    float* hisA = alloc((size_t)400 * 64);
    float* cddA = alloc((size_t)40 * 64);
    float* cddR = alloc((size_t)64 * 768);
    float* userR = alloc((size_t)8 * 768);
    float* user0 = alloc((size_t)8 * 768);
    float* psM = alloc((size_t)8 * 400);
    int*   kidI = (int*)alloc(3200);

    auto gemm = [&](const float* A, const float* B2, float* C, int M, int N, int Kd,
                    int epi, const float* bias) {
        dim3 grid((N + 63) / 64, (M + 63) / 64);
        gemm_kernel<<<grid, 256, 0, stream>>>(A, B2, C, M, N, Kd, epi, bias);
    };

    auto run_tf = [&](float* Xc, const float* maskc, int nseq, int S,
                      const float* Wq, const float* Wk, const float* Wv, const float* Wo,
                      const float* W1, const float* W2, float* outH, float* clsD) {
        int R = nseq * S;
        gemm(Xc, Wq, Qa, R, DIM, DIM, 0, nullptr);
        gemm(Xc, Wk, Ka, R, DIM, DIM, 0, nullptr);
        gemm(Xc, Wv, Va, R, DIM, DIM, 0, nullptr);
        attn_scores_kernel<<<nseq * NHEAD * S, 256, 0, stream>>>(Qa, Ka, maskc, SF, S);
        attn_av_kernel<<<nseq * NHEAD * (S / 4), dim3(64, 4), 0, stream>>>(SF, Va, Oa, S);
        gemm(Oa, Wo, Qa, R, DIM, DIM, 0, nullptr);           // Qa reused as o-proj out
        add_ln_kernel<<<R, 256, 0, stream>>>(Xc, Qa, Ha);
        gemm(Ha, W1, SF, R, FFDIM, DIM, 1, nullptr);         // gelu epilogue
        gemm(SF, W2, Qa, R, DIM, FFDIM, 0, nullptr);
        add_ln_kernel<<<R, 256, 0, stream>>>(Ha, Qa, outH);
        cls_copy_kernel<<<nseq, 256, 0, stream>>>(outH, clsD, S);
    };

    // ---- candidate news: BERT encode -> CLS -> proj ----
    build_prefix_kernel<<<40, 256, 0, stream>>>(cdd_sub, cdd_mask, cdd_amask, Pa, cddA, 0);
    emb_pool_kernel<<<40 * 64, 256, 0, stream>>>(Pa, cdd_enc, emb, Xa, 0);
    run_tf(Xa, cddA, 40, 64, bWq, bWk, bWv, bWo, bW1, bW2, Xa, cddC);
    gemm(cddC, pW, cddR, 40, DIM, DIM, 2, pb);

    // ---- history news encoder: 8 chunks of 50 sequences ----
    for (int c = 0; c < 8; c++) {
        int seq0 = c * 50;
        build_prefix_kernel<<<50, 256, 0, stream>>>(his_sub, his_mask, his_amask, Pa, hisA, seq0);
        emb_pool_kernel<<<50 * 64, 256, 0, stream>>>(Pa, his_enc, emb, Xa, seq0);
        run_tf(Xa, hisA + (size_t)seq0 * 64, 50, 64, eWq, eWk, eWv, eWo, eW1, eW2,
               hisH + (size_t)seq0 * 64 * 768, hisC + (size_t)seq0 * 768);
    }

    // ---- user encoder + matching reducer ----
    user_pool_kernel<<<8, 256, 0, stream>>>(hisC, qU, user0);
    topk_kernel<<<400, 256, 0, stream>>>(hisH, user0, hisA, out + 40, kidI, psM);
    gather_kernel<<<3200, 256, 0, stream>>>(hisH, kidI, Xa);

    // ---- user BERT over 400 selected terms (bert weights), S = 400 ----
    run_tf(Xa, psM, 8, 400, bWq, bWk, bWv, bWo, bW1, bW2, Xa, userC);
    gemm(userC, pW, userR, 8, DIM, DIM, 2, pb);

    // ---- final scores + log_softmax ----
    final_kernel<<<8, 256, 0, stream>>>(cddR, userR, out);
}

// Round 2
// 6076.134 us; speedup vs baseline: 2.0139x; 2.0139x over previous
//
#include <hip/hip_runtime.h>
#include <math.h>

#define DIM 768
#define NHEAD 12
#define DHEAD 64
#define FFDIM 3072

typedef _Float16 v8h __attribute__((ext_vector_type(8)));
typedef float v4f __attribute__((ext_vector_type(4)));

__device__ __forceinline__ float gelu_f(float x) {
    float x3 = x * x * x;
    return 0.5f * x * (1.0f + tanhf(0.7978845608028654f * (x + 0.044715f * x3)));
}

// ================= MFMA GEMM: C[M,N] = sum_t A_t[M,K] @ B_t[N,K]^T ==================
// fp16 inputs (split terms), fp32 accumulate. 128x128 tile, BK=32, 256 thr (4 waves).
// epi 0: C[z] = acc*cdiv ; epi 1: g=gelu(acc*cdiv), dual fp16 store g*gscale -> G1,G2
struct GemmP {
    const _Float16* A[3];
    const _Float16* B[3][3];   // [z][term]
    float* C[3];
    _Float16* G1; _Float16* G2;
};

#define LDK 40   // padded LDS row stride in halves (80B: 16B-aligned, conflict-free)

__global__ __launch_bounds__(256) void gemm_mfma(GemmP p, int M, int N, int K,
                                                 int nt, int epi, float cdiv, float gscale)
{
    __shared__ _Float16 As[128 * LDK];
    __shared__ _Float16 Bs[128 * LDK];
    const int z = blockIdx.z;
    const int tid = threadIdx.x;
    const int wave = tid >> 6, lane = tid & 63;
    const int lm = lane & 15, kg = lane >> 4;
    const int row0 = blockIdx.y << 7, col0 = blockIdx.x << 7;
    const int wm = (wave >> 1) << 6, wn = (wave & 1) << 6;
    const int sr = tid >> 2, sc = (tid & 3) << 3;
    v4f acc[4][4];
#pragma unroll
    for (int i = 0; i < 4; i++)
#pragma unroll
        for (int j = 0; j < 4; j++) acc[i][j] = (v4f){0.f, 0.f, 0.f, 0.f};

    for (int t = 0; t < nt; t++) {
        const _Float16* Ab = p.A[t] + (size_t)row0 * K;
        const _Float16* Bb = p.B[z][t] + (size_t)col0 * K;
        for (int k0 = 0; k0 < K; k0 += 32) {
            __syncthreads();
            *(v8h*)(As + sr * LDK + sc)        = *(const v8h*)(Ab + (size_t)sr * K + k0 + sc);
            *(v8h*)(As + (sr + 64) * LDK + sc) = *(const v8h*)(Ab + (size_t)(sr + 64) * K + k0 + sc);
            *(v8h*)(Bs + sr * LDK + sc)        = *(const v8h*)(Bb + (size_t)sr * K + k0 + sc);
            *(v8h*)(Bs + (sr + 64) * LDK + sc) = *(const v8h*)(Bb + (size_t)(sr + 64) * K + k0 + sc);
            __syncthreads();
            v8h af[4], bf[4];
#pragma unroll
            for (int i = 0; i < 4; i++) {
                af[i] = *(const v8h*)(As + (wm + (i << 4) + lm) * LDK + (kg << 3));
                bf[i] = *(const v8h*)(Bs + (wn + (i << 4) + lm) * LDK + (kg << 3));
            }
#pragma unroll
            for (int i = 0; i < 4; i++)
#pragma unroll
                for (int j = 0; j < 4; j++)
                    acc[i][j] = __builtin_amdgcn_mfma_f32_16x16x32_f16(af[i], bf[j], acc[i][j], 0, 0, 0);
        }
    }
    float* C = p.C[z];
#pragma unroll
    for (int i = 0; i < 4; i++) {
        int rb = row0 + wm + (i << 4) + (kg << 2);
#pragma unroll
        for (int j = 0; j < 4; j++) {
            int cc = col0 + wn + (j << 4) + lm;
#pragma unroll
            for (int r = 0; r < 4; r++) {
                float c = acc[i][j][r] * cdiv;
                size_t idx = (size_t)(rb + r) * N + cc;
                if (epi == 0) {
                    C[idx] = c;
                } else {
                    float gv = gelu_f(c) * gscale;
                    _Float16 g1 = (_Float16)gv;
                    p.G1[idx] = g1;
                    p.G2[idx] = (_Float16)(gv - (float)g1);
                }
            }
        }
    }
}

// ---------------- fp32 -> 2-way fp16 split (Dekker), with power-of-2 scale ----------------
__global__ __launch_bounds__(256) void split2_kernel(const float* __restrict__ X,
    _Float16* __restrict__ A1, _Float16* __restrict__ A2, float s, int n)
{
    int i = (blockIdx.x * 256 + threadIdx.x) * 4;
    if (i >= n) return;
    float4 x = *(const float4*)(X + i);
    float v[4] = {x.x, x.y, x.z, x.w};
#pragma unroll
    for (int u = 0; u < 4; u++) {
        float xs = v[u] * s;
        _Float16 a = (_Float16)xs;
        A1[i + u] = a;
        A2[i + u] = (_Float16)(xs - (float)a);
    }
}

// ---------------- weight transpose + split: W[K,N] -> B1,B2 [N,K] (x64 scale) ----------------
__global__ __launch_bounds__(256) void wsplit_kernel(const float* __restrict__ W,
    _Float16* __restrict__ B1, _Float16* __restrict__ B2, int Kd, int N)
{
    int id = blockIdx.x * 256 + threadIdx.x;
    if (id >= Kd * N) return;
    int n = id / Kd, k = id - n * Kd;
    float v = W[(size_t)k * N + n] * 64.f;
    _Float16 b1 = (_Float16)v;
    B1[id] = b1;
    if (B2) B2[id] = (_Float16)(v - (float)b1);
}

// ---------------- prefix build + pooled attention mask ----------------
__global__ __launch_bounds__(256) void build_prefix_kernel(const int* __restrict__ sub,
    const float* __restrict__ mask, const float* __restrict__ amask,
    float* __restrict__ P, float* __restrict__ attn_out, int seq0)
{
    __shared__ float pref[64 * 64];
    int gl = blockIdx.x;
    int g = seq0 + gl;
    int tid = threadIdx.x;
    for (int t = tid; t < 4096; t += 256) pref[t] = 0.f;
    __syncthreads();
    if (tid < 64) {
        int r = sub[((size_t)g * 64 + tid) * 2 + 0];
        int c = sub[((size_t)g * 64 + tid) * 2 + 1];
        pref[(r << 6) + c] = 1.0f;
    }
    __syncthreads();
    float m = mask[g];
    int lane = tid & 63, w = tid >> 6;
    for (int s = (w << 4); s < (w << 4) + 16; s++) {
        float v = pref[(s << 6) + lane] * m;
        float rs = v;
#pragma unroll
        for (int o = 32; o; o >>= 1) rs += __shfl_down(rs, o);
        rs = __shfl(rs, 0);
        float nv = v / fmaxf(rs, 1e-12f);
        P[(((size_t)gl << 6) + s) * 64 + lane] = nv;
        float av = nv * amask[((size_t)g << 6) + lane];
#pragma unroll
        for (int o = 32; o; o >>= 1) av += __shfl_down(av, o);
        if (lane == 0) attn_out[((size_t)g << 6) + s] = av;
    }
}

// ---------------- subword->token embedding pooling ----------------
__global__ __launch_bounds__(256) void emb_pool_kernel(const float* __restrict__ P,
    const int* __restrict__ enc, const float* __restrict__ emb,
    float* __restrict__ X, int seq0)
{
    int s = blockIdx.x & 63;
    int gl = blockIdx.x >> 6;
    int g = seq0 + gl;
    int tid = threadIdx.x;
    __shared__ float pw[64];
    __shared__ int tk[64];
    if (tid < 64) {
        pw[tid] = P[(((size_t)gl << 6) + s) * 64 + tid];
        tk[tid] = enc[((size_t)g << 6) + tid];
    }
    __syncthreads();
    float a0 = 0.f, a1 = 0.f, a2 = 0.f;
    for (int t = 0; t < 64; t++) {
        float w = pw[t];
        if (w != 0.f) {
            const float* er = emb + (size_t)tk[t] * DIM;
            a0 = fmaf(w, er[tid], a0);
            a1 = fmaf(w, er[tid + 256], a1);
            a2 = fmaf(w, er[tid + 512], a2);
        }
    }
    size_t ro = (((size_t)gl << 6) + s) * DIM;
    X[ro + tid] = a0; X[ro + tid + 256] = a1; X[ro + tid + 512] = a2;
}

// ---------------- fused S=64 attention (one block per seq,head), fp32, fp16-split out ----
__global__ __launch_bounds__(256) void attn_fused64(const float* __restrict__ Q,
    const float* __restrict__ Km, const float* __restrict__ V,
    const float* __restrict__ mask, _Float16* __restrict__ o1, _Float16* __restrict__ o2)
{
    __shared__ float Ks[64 * 65];
    __shared__ float Vs[64 * 65];
    __shared__ float Qs[64 * 65];
    int h = blockIdx.x % NHEAD;
    int g = blockIdx.x / NHEAD;
    int tid = threadIdx.x, lane = tid & 63, w = tid >> 6;
    {
        int r = tid >> 2, c0 = (tid & 3) << 4;
        const float* qp = Q  + ((size_t)g * 64 + r) * DIM + h * DHEAD + c0;
        const float* kp = Km + ((size_t)g * 64 + r) * DIM + h * DHEAD + c0;
        const float* vp = V  + ((size_t)g * 64 + r) * DIM + h * DHEAD + c0;
#pragma unroll
        for (int u = 0; u < 16; u += 4) {
            float4 qv = *(const float4*)(qp + u);
            float4 kv = *(const float4*)(kp + u);
            float4 vv = *(const float4*)(vp + u);
            int o = r * 65 + c0 + u;
            Qs[o+0]=qv.x; Qs[o+1]=qv.y; Qs[o+2]=qv.z; Qs[o+3]=qv.w;
            Ks[o+0]=kv.x; Ks[o+1]=kv.y; Ks[o+2]=kv.z; Ks[o+3]=kv.w;
            Vs[o+0]=vv.x; Vs[o+1]=vv.y; Vs[o+2]=vv.z; Vs[o+3]=vv.w;
        }
    }
    __syncthreads();
    float mk = mask[(size_t)g * 64 + lane] > 0.f ? 0.f : -1e9f;
    for (int il = 0; il < 16; il++) {
        int i = (w << 4) + il;
        // lane = j: logit
        float d = 0.f;
        for (int t = 0; t < 64; t++) d = fmaf(Qs[i * 65 + t], Ks[lane * 65 + t], d);
        float l = d * 0.125f + mk;
        float mx = l;
#pragma unroll
        for (int o = 32; o; o >>= 1) mx = fmaxf(mx, __shfl_xor(mx, o));
        float e = expf(l - mx);
        float s = e;
#pragma unroll
        for (int o = 32; o; o >>= 1) s += __shfl_xor(s, o);
        float p = e / s;
        // lane = d: o_d = sum_j p_j V[j][d]
        float acc = 0.f;
        for (int j = 0; j < 64; j++) {
            float pj = __shfl(p, j);
            acc = fmaf(pj, Vs[j * 65 + lane], acc);
        }
        size_t ob = ((size_t)g * 64 + i) * DIM + h * DHEAD + lane;
        float os = acc * 64.f;
        _Float16 h1 = (_Float16)os;
        o1[ob] = h1;
        o2[ob] = (_Float16)(os - (float)h1);
    }
}

// ---------------- attention scores + softmax (per g,h,i) — used for S=400 ----------------
__global__ __launch_bounds__(256) void attn_scores_kernel(const float* __restrict__ Q,
    const float* __restrict__ Km, const float* __restrict__ mask,
    float* __restrict__ P, int S)
{
    __shared__ float qs[64];
    __shared__ float ps[400];
    __shared__ float red[256];
    int i = blockIdx.x % S;
    int h = (blockIdx.x / S) % NHEAD;
    int g = blockIdx.x / (S * NHEAD);
    int tid = threadIdx.x;
    if (tid < 64) qs[tid] = Q[((size_t)g * S + i) * DIM + h * DHEAD + tid];
    __syncthreads();
    for (int j = tid; j < S; j += 256) {
        const float4* kr = (const float4*)(Km + ((size_t)g * S + j) * DIM + h * DHEAD);
        float d = 0.f;
#pragma unroll
        for (int t = 0; t < 16; t++) {
            float4 k4 = kr[t];
            d = fmaf(qs[4 * t + 0], k4.x, d);
            d = fmaf(qs[4 * t + 1], k4.y, d);
            d = fmaf(qs[4 * t + 2], k4.z, d);
            d = fmaf(qs[4 * t + 3], k4.w, d);
        }
        float mm = mask[(size_t)g * S + j];
        ps[j] = d * 0.125f + (mm > 0.f ? 0.f : -1e9f);
    }
    __syncthreads();
    float lm = -INFINITY;
    for (int j = tid; j < S; j += 256) lm = fmaxf(lm, ps[j]);
    red[tid] = lm; __syncthreads();
    for (int o = 128; o; o >>= 1) { if (tid < o) red[tid] = fmaxf(red[tid], red[tid + o]); __syncthreads(); }
    float mx = red[0];
    __syncthreads();
    float ls = 0.f;
    for (int j = tid; j < S; j += 256) { float e = expf(ps[j] - mx); ps[j] = e; ls += e; }
    red[tid] = ls; __syncthreads();
    for (int o = 128; o; o >>= 1) { if (tid < o) red[tid] += red[tid + o]; __syncthreads(); }
    float inv = 1.0f / red[0];
    float* prow = P + ((size_t)(g * NHEAD + h) * S + i) * S;
    for (int j = tid; j < S; j += 256) prow[j] = ps[j] * inv;
}

// ---------------- attention output O = P @ V, fp16-split out (S=400 path) ----------------
__global__ void attn_av_kernel(const float* __restrict__ P, const float* __restrict__ V,
    _Float16* __restrict__ o1, _Float16* __restrict__ o2, int S)
{
    int d = threadIdx.x;
    int isub = threadIdx.y;
    int nblk = S >> 2;
    int ib = blockIdx.x % nblk;
    int h = (blockIdx.x / nblk) % NHEAD;
    int g = blockIdx.x / (nblk * NHEAD);
    int i = (ib << 2) + isub;
    const float* pr = P + ((size_t)(g * NHEAD + h) * S + i) * S;
    const float* vb = V + (size_t)g * S * DIM + h * DHEAD + d;
    float acc = 0.f;
    for (int j = 0; j < S; j++) acc = fmaf(pr[j], vb[(size_t)j * DIM], acc);
    size_t ob = ((size_t)g * S + i) * DIM + h * DHEAD + d;
    float os = acc * 64.f;
    _Float16 h1 = (_Float16)os;
    o1[ob] = h1;
    o2[ob] = (_Float16)(os - (float)h1);
}

// ---------------- h = LayerNorm(X + Y) ----------------
__global__ __launch_bounds__(256) void add_ln_kernel(const float* __restrict__ X,
    const float* __restrict__ Y, float* __restrict__ Out)
{
    int r = blockIdx.x, tid = threadIdx.x;
    size_t base = (size_t)r * DIM;
    float v0 = X[base + tid] + Y[base + tid];
    float v1 = X[base + tid + 256] + Y[base + tid + 256];
    float v2 = X[base + tid + 512] + Y[base + tid + 512];
    __shared__ float red[256];
    red[tid] = v0 + v1 + v2; __syncthreads();
    for (int o = 128; o; o >>= 1) { if (tid < o) red[tid] += red[tid + o]; __syncthreads(); }
    float mu = red[0] * (1.f / 768.f);
    __syncthreads();
    float d0 = v0 - mu, d1 = v1 - mu, d2 = v2 - mu;
    red[tid] = d0 * d0 + d1 * d1 + d2 * d2; __syncthreads();
    for (int o = 128; o; o >>= 1) { if (tid < o) red[tid] += red[tid + o]; __syncthreads(); }
    float rstd = rsqrtf(red[0] * (1.f / 768.f) + 1e-12f);
    Out[base + tid] = d0 * rstd;
    Out[base + tid + 256] = d1 * rstd;
    Out[base + tid + 512] = d2 * rstd;
}

__global__ void cls_copy_kernel(const float* __restrict__ H, float* __restrict__ cls, int S) {
    int g = blockIdx.x, tid = threadIdx.x;
    size_t src = (size_t)g * S * DIM;
    cls[(size_t)g * DIM + tid]       = H[src + tid];
    cls[(size_t)g * DIM + tid + 256] = H[src + tid + 256];
    cls[(size_t)g * DIM + tid + 512] = H[src + tid + 512];
}

// ---------------- legacy fp32 SIMT GEMM (tiny proj GEMMs only) ----------------
__global__ __launch_bounds__(256) void gemm_kernel(const float* __restrict__ A,
    const float* __restrict__ B, float* __restrict__ C,
    int M, int N, int Kd, int epi, const float* __restrict__ bias)
{
    __shared__ float As[16][64];
    __shared__ float Bs[16][64];
    int tid = threadIdx.x;
    int tx = tid & 15, ty = tid >> 4;
    int row0 = blockIdx.y << 6, col0 = blockIdx.x << 6;
    int ar = tid >> 2, ak = (tid & 3) << 2;
    int bc = tid & 63, bk0 = tid >> 6;
    const float* Ap = A + (size_t)(row0 + ar) * Kd + ak;
    const float* Bp = B + (size_t)bk0 * N + col0 + bc;
    bool aval = (row0 + ar) < M;
    float acc[4][4];
#pragma unroll
    for (int i = 0; i < 4; i++)
#pragma unroll
        for (int j = 0; j < 4; j++) acc[i][j] = 0.f;
    for (int k0 = 0; k0 < Kd; k0 += 16) {
        float4 a4 = make_float4(0.f, 0.f, 0.f, 0.f);
        if (aval) a4 = *(const float4*)(Ap + k0);
        As[ak + 0][ar] = a4.x; As[ak + 1][ar] = a4.y;
        As[ak + 2][ar] = a4.z; As[ak + 3][ar] = a4.w;
#pragma unroll
        for (int i = 0; i < 4; i++)
            Bs[bk0 + 4 * i][bc] = Bp[(size_t)(k0 + 4 * i) * N];
        __syncthreads();
#pragma unroll
        for (int kk = 0; kk < 16; kk++) {
            float4 av = *(const float4*)&As[kk][ty << 2];
            float4 bv = *(const float4*)&Bs[kk][tx << 2];
            float aa[4] = {av.x, av.y, av.z, av.w};
            float bb[4] = {bv.x, bv.y, bv.z, bv.w};
#pragma unroll
            for (int i = 0; i < 4; i++)
#pragma unroll
                for (int j = 0; j < 4; j++)
                    acc[i][j] = fmaf(aa[i], bb[j], acc[i][j]);
        }
        __syncthreads();
    }
#pragma unroll
    for (int i = 0; i < 4; i++) {
        int r = row0 + (ty << 2) + i;
        if (r >= M) continue;
        float v[4];
#pragma unroll
        for (int j = 0; j < 4; j++) {
            float x = acc[i][j];
            if (epi == 1) x = gelu_f(x);
            else if (epi == 2) x = tanhf(x + bias[col0 + (tx << 2) + j]);
            v[j] = x;
        }
        *(float4*)(C + (size_t)r * N + col0 + (tx << 2)) = make_float4(v[0], v[1], v[2], v[3]);
    }
}

// ---------------- user attention pooling ----------------
__global__ __launch_bounds__(256) void user_pool_kernel(const float* __restrict__ cls,
    const float* __restrict__ qU, float* __restrict__ user0)
{
    int b = blockIdx.x, tid = threadIdx.x;
    __shared__ float red[256];
    __shared__ float wv[64];
    const float scale = 0.03608439182435161f;
    for (int n = 0; n < 50; n++) {
        const float* cr = cls + ((size_t)(b * 50 + n)) * DIM;
        float d = 0.f;
        for (int t = tid; t < DIM; t += 256) d = fmaf(cr[t], qU[t], d);
        red[tid] = d; __syncthreads();
        for (int o = 128; o; o >>= 1) { if (tid < o) red[tid] += red[tid + o]; __syncthreads(); }
        if (tid == 0) wv[n] = red[0] * scale;
        __syncthreads();
    }
    if (tid == 0) {
        float mx = -INFINITY;
        for (int n = 0; n < 50; n++) mx = fmaxf(mx, wv[n]);
        float s = 0.f;
        for (int n = 0; n < 50; n++) { float e = expf(wv[n] - mx); wv[n] = e; s += e; }
        float inv = 1.f / s;
        for (int n = 0; n < 50; n++) wv[n] *= inv;
    }
    __syncthreads();
    for (int d = tid; d < DIM; d += 256) {
        float a = 0.f;
        for (int n = 0; n < 50; n++) a = fmaf(wv[n], cls[((size_t)(b * 50 + n)) * DIM + d], a);
        user0[(size_t)b * DIM + d] = a;
    }
}

// ---------------- personalized-term scores + stable top-8 ----------------
__global__ __launch_bounds__(256) void topk_kernel(const float* __restrict__ hid,
    const float* __restrict__ user0, const float* __restrict__ attn,
    float* __restrict__ kid_f, int* __restrict__ kid_i, float* __restrict__ ps_mask)
{
    int bn = blockIdx.x;
    int b = bn / 50;
    int tid = threadIdx.x, lane = tid & 63, w = tid >> 6;
    __shared__ float sc[64];
    const float* u = user0 + (size_t)b * DIM;
    const float scale = 0.03608439182435161f;
    for (int s = w; s < 64; s += 4) {
        const float* hr = hid + ((size_t)bn * 64 + s) * DIM;
        float d = 0.f;
        for (int t = lane; t < DIM; t += 64) d = fmaf(hr[t], u[t], d);
#pragma unroll
        for (int o = 32; o; o >>= 1) d += __shfl_down(d, o);
        if (lane == 0) {
            float a = attn[(size_t)bn * 64 + s];
            sc[s] = (a > 0.f) ? d * scale : -1e9f;
        }
    }
    __syncthreads();
    if (tid == 0) {
        unsigned long long used = 0ull;
        for (int k = 0; k < 8; k++) {
            float best = -INFINITY; int bi = 0;
            for (int s = 0; s < 64; s++) {
                if ((used >> s) & 1ull) continue;
                if (sc[s] > best) { best = sc[s]; bi = s; }
            }
            used |= (1ull << bi);
            kid_i[bn * 8 + k] = bi;
            kid_f[bn * 8 + k] = (float)bi;
            ps_mask[bn * 8 + k] = attn[(size_t)bn * 64 + bi];
        }
    }
}

__global__ void gather_kernel(const float* __restrict__ hid, const int* __restrict__ kid_i,
    float* __restrict__ X)
{
    int r = blockIdx.x, tid = threadIdx.x;
    int s = kid_i[r];
    int bn = r >> 3;
    const float* src = hid + ((size_t)bn * 64 + s) * DIM;
    float* dst = X + (size_t)r * DIM;
    dst[tid] = src[tid];
    dst[tid + 256] = src[tid + 256];
    dst[tid + 512] = src[tid + 512];
}

__global__ __launch_bounds__(256) void final_kernel(const float* __restrict__ cdd_repr,
    const float* __restrict__ user_repr, float* __restrict__ out)
{
    int b = blockIdx.x, tid = threadIdx.x;
    __shared__ float red[256];
    __shared__ float sc[5];
    const float scale = 0.03608439182435161f;
    for (int c = 0; c < 5; c++) {
        const float* cr = cdd_repr + ((size_t)(b * 5 + c)) * DIM;
        const float* ur = user_repr + (size_t)b * DIM;
        float d = 0.f;
        for (int t = tid; t < DIM; t += 256) d = fmaf(cr[t], ur[t], d);
        red[tid] = d; __syncthreads();
        for (int o = 128; o; o >>= 1) { if (tid < o) red[tid] += red[tid + o]; __syncthreads(); }
        if (tid == 0) sc[c] = red[0] * scale;
        __syncthreads();
    }
    if (tid == 0) {
        float mx = -INFINITY;
        for (int c = 0; c < 5; c++) mx = fmaxf(mx, sc[c]);
        float s = 0.f;
        for (int c = 0; c < 5; c++) s += expf(sc[c] - mx);
        float lse = logf(s) + mx;
        for (int c = 0; c < 5; c++) out[b * 5 + c] = sc[c] - lse;
    }
}

extern "C" void kernel_launch(void* const* d_in, const int* in_sizes, int n_in,
                              void* d_out, int out_size, void* d_ws, size_t ws_size,
                              hipStream_t stream)
{
    (void)in_sizes; (void)n_in; (void)out_size; (void)ws_size;
    const int*   cdd_sub   = (const int*)d_in[0];
    const int*   his_sub   = (const int*)d_in[1];
    const int*   cdd_enc   = (const int*)d_in[2];
    const int*   his_enc   = (const int*)d_in[3];
    const float* cdd_mask  = (const float*)d_in[4];
    const float* his_mask  = (const float*)d_in[5];
    const float* cdd_amask = (const float*)d_in[6];
    const float* his_amask = (const float*)d_in[7];
    const float* emb = (const float*)d_in[8];
    const float* bWsrc[6] = {(const float*)d_in[9],  (const float*)d_in[10], (const float*)d_in[11],
                             (const float*)d_in[12], (const float*)d_in[13], (const float*)d_in[14]};
    const float* eWsrc[6] = {(const float*)d_in[15], (const float*)d_in[16], (const float*)d_in[17],
                             (const float*)d_in[18], (const float*)d_in[19], (const float*)d_in[20]};
    const float* qU = (const float*)d_in[21];
    const float* pW = (const float*)d_in[22];
    const float* pb = (const float*)d_in[23];
    float* out = (float*)d_out;

    // ---- workspace carve (f32 units; total ~48.1M f32 = 192 MB) ----
    float* ws = (float*)d_ws;
    size_t off = 0;
    auto allocF = [&](size_t n) { float* p = ws + off; off += n; return p; };
    float* R_X  = allocF(2457600);     // X / H (in-place)
    float* R_Q  = allocF(2457600);     // Q / Wo-out / W2-out
    float* R_K  = allocF(2457600);     // K ; g1 (fp16) aliases K+V during FFN
    float* R_V  = allocF(2457600);
    float* R_Pa = allocF(204800);
    _Float16* s1h = (_Float16*)allocF(1228800);   // X/O/H split term1 (R x 768 halves)
    _Float16* s2h = (_Float16*)allocF(1228800);
    _Float16* g2h = (_Float16*)allocF(4915200);   // gelu split term2 (R x 3072 halves)
    float* hisH  = allocF(19660800);   // his_hidden; also user attn score buffer later
    float* hisC  = allocF(307200);
    float* cddC  = allocF(30720);
    float* userC = allocF(6144);
    float* hisA  = allocF(25600);
    float* cddA  = allocF(2560);
    float* cddR  = allocF(30720);
    float* userR = allocF(6144);
    float* user0 = allocF(6144);
    float* psM   = allocF(3200);
    int*   kidI  = (int*)allocF(3200);
    auto allocH = [&](size_t nh) { _Float16* p = (_Float16*)(ws + off); off += (nh + 1) / 2; return p; };
    size_t wsz[6] = {589824, 589824, 589824, 589824, 2359296, 2359296};
    _Float16 *eB1[6], *eB2[6], *bB1[6];
    for (int i = 0; i < 6; i++) eB1[i] = allocH(wsz[i]);
    for (int i = 0; i < 6; i++) eB2[i] = allocH(wsz[i]);
    for (int i = 0; i < 6; i++) bB1[i] = allocH(wsz[i]);
    _Float16* g1h = (_Float16*)R_K;    // 9,830,400 halves over K+V

    // ---- weight transpose+split (x64 scale) ----
    int wk[6] = {768, 768, 768, 768, 768, 3072};
    int wn[6] = {768, 768, 768, 768, 3072, 768};
    for (int i = 0; i < 6; i++) {
        int n = wk[i] * wn[i];
        wsplit_kernel<<<(n + 255) / 256, 256, 0, stream>>>(eWsrc[i], eB1[i], eB2[i], wk[i], wn[i]);
        wsplit_kernel<<<(n + 255) / 256, 256, 0, stream>>>(bWsrc[i], bB1[i], nullptr, wk[i], wn[i]);
    }

    // ---- one transformer pass over R_X ----
    auto tf = [&](const float* maskp, int nseq, int S, _Float16* const* B1, _Float16* const* B2,
                  int nt, float* outH, float* clsD, float* scoreBuf) {
        int R = nseq * S, MB = R >> 7;
        int nsplit = (R * 768 / 4 + 255) / 256;
        split2_kernel<<<nsplit, 256, 0, stream>>>(R_X, s1h, s2h, 64.f, R * 768);
        GemmP gq{};
        gq.A[0] = s1h; gq.A[1] = s1h; gq.A[2] = s2h;
        for (int z = 0; z < 3; z++) {
            gq.B[z][0] = B1[z]; gq.B[z][1] = B2 ? B2[z] : nullptr; gq.B[z][2] = B1[z];
        }
        gq.C[0] = R_Q; gq.C[1] = R_K; gq.C[2] = R_V;
        gemm_mfma<<<dim3(6, MB, 3), 256, 0, stream>>>(gq, R, 768, 768, nt, 0, 1.f / 4096.f, 0.f);
        if (S == 64) {
            attn_fused64<<<nseq * NHEAD, 256, 0, stream>>>(R_Q, R_K, R_V, maskp, s1h, s2h);
        } else {
            attn_scores_kernel<<<nseq * NHEAD * S, 256, 0, stream>>>(R_Q, R_K, maskp, scoreBuf, S);
            attn_av_kernel<<<nseq * NHEAD * (S / 4), dim3(64, 4), 0, stream>>>(scoreBuf, R_V, s1h, s2h, S);
        }
        GemmP go{};
        go.A[0] = s1h; go.A[1] = s1h; go.A[2] = s2h;
        go.B[0][0] = B1[3]; go.B[0][1] = B2 ? B2[3] : nullptr; go.B[0][2] = B1[3];
        go.C[0] = R_Q;
        gemm_mfma<<<dim3(6, MB, 1), 256, 0, stream>>>(go, R, 768, 768, nt, 0, 1.f / 4096.f, 0.f);
        add_ln_kernel<<<R, 256, 0, stream>>>(R_X, R_Q, R_X);
        split2_kernel<<<nsplit, 256, 0, stream>>>(R_X, s1h, s2h, 1.f, R * 768);
        GemmP g1{};
        g1.A[0] = s1h; g1.A[1] = s1h; g1.A[2] = s2h;
        g1.B[0][0] = B1[4]; g1.B[0][1] = B2 ? B2[4] : nullptr; g1.B[0][2] = B1[4];
        g1.G1 = g1h; g1.G2 = g2h;
        gemm_mfma<<<dim3(24, MB, 1), 256, 0, stream>>>(g1, R, 3072, 768, nt, 1, 1.f / 64.f, 16.f);
        GemmP g2{};
        g2.A[0] = g1h; g2.A[1] = g1h; g2.A[2] = g2h;
        g2.B[0][0] = B1[5]; g2.B[0][1] = B2 ? B2[5] : nullptr; g2.B[0][2] = B1[5];
        g2.C[0] = R_Q;
        gemm_mfma<<<dim3(6, MB, 1), 256, 0, stream>>>(g2, R, 768, 3072, nt, 0, 1.f / 1024.f, 0.f);
        add_ln_kernel<<<R, 256, 0, stream>>>(R_X, R_Q, outH);
        cls_copy_kernel<<<nseq, 256, 0, stream>>>(outH, clsD, S);
    };

    // ---- candidate news (bert, 1-term fp16) ----
    build_prefix_kernel<<<40, 256, 0, stream>>>(cdd_sub, cdd_mask, cdd_amask, R_Pa, cddA, 0);
    emb_pool_kernel<<<40 * 64, 256, 0, stream>>>(R_Pa, cdd_enc, emb, R_X, 0);
    tf(cddA, 40, 64, bB1, nullptr, 1, R_X, cddC, nullptr);
    gemm_kernel<<<dim3(12, 1), 256, 0, stream>>>(cddC, pW, cddR, 40, 768, 768, 2, pb);

    // ---- history news (encN, 3-product fp16-split ~ fp32 accurate) ----
    for (int c = 0; c < 8; c++) {
        int seq0 = c * 50;
        build_prefix_kernel<<<50, 256, 0, stream>>>(his_sub, his_mask, his_amask, R_Pa, hisA, seq0);
        emb_pool_kernel<<<50 * 64, 256, 0, stream>>>(R_Pa, his_enc, emb, R_X, seq0);
        tf(hisA + (size_t)seq0 * 64, 50, 64, eB1, eB2, 3,
           hisH + (size_t)seq0 * 64 * DIM, hisC + (size_t)seq0 * DIM, nullptr);
    }

    // ---- user encoder + matching reducer (fp32) ----
    user_pool_kernel<<<8, 256, 0, stream>>>(hisC, qU, user0);
    topk_kernel<<<400, 256, 0, stream>>>(hisH, user0, hisA, out + 40, kidI, psM);
    gather_kernel<<<3200, 256, 0, stream>>>(hisH, kidI, R_X);

    // ---- user BERT over selected terms (bert, 1-term; scores alias hisH) ----
    tf(psM, 8, 400, bB1, nullptr, 1, R_X, userC, hisH);
    gemm_kernel<<<dim3(12, 1), 256, 0, stream>>>(userC, pW, userR, 8, 768, 768, 2, pb);

    final_kernel<<<8, 256, 0, stream>>>(cddR, userR, out);
}

// Round 3
// 3629.330 us; speedup vs baseline: 3.3716x; 1.6742x over previous
//
#include <hip/hip_runtime.h>
#include <math.h>

#define DIM 768
#define NHEAD 12
#define DHEAD 64
#define FFDIM 3072

typedef _Float16 v8h __attribute__((ext_vector_type(8)));
typedef float v4f __attribute__((ext_vector_type(4)));

__device__ __forceinline__ float gelu_f(float x) {
    float x3 = x * x * x;
    return 0.5f * x * (1.0f + tanhf(0.7978845608028654f * (x + 0.044715f * x3)));
}

// async global->LDS, 16B per lane; lds base must be wave-uniform (HW adds lane*16)
__device__ __forceinline__ void gl_lds16(const _Float16* g, _Float16* l) {
    __builtin_amdgcn_global_load_lds(
        (const __attribute__((address_space(1))) unsigned int*)(g),
        (__attribute__((address_space(3))) unsigned int*)(l),
        16, 0, 0);
}

// ================= MFMA GEMM v2: C = (A1+A2)(B1+B2) - A2B2 (nt=3) or A1B1 (nt=1) =====
// fp16 split inputs, fp32 accum. 128x128 tile, BK=32, 256 thr. global_load_lds staging.
struct GemmP {
    const _Float16* A1; const _Float16* A2;
    const _Float16* B1[3]; const _Float16* B2[3];
    float* C[3];
    _Float16* G1; _Float16* G2;
};

__global__ __launch_bounds__(256) void gemm_mfma(GemmP p, int M, int N, int K,
                                                 int nt, int epi, float cdiv, float gscale)
{
    __shared__ _Float16 sm[4][128 * 32];
    const int z = blockIdx.z;
    const int tid = threadIdx.x;
    const int w = tid >> 6, lane = tid & 63;
    const int lm = lane & 15, kg = lane >> 4;
    const int row0 = blockIdx.y << 7, col0 = blockIdx.x << 7;
    const int wm = (w >> 1) << 6, wn = (w & 1) << 6;
    const int rl = (w << 4) + (lane >> 2);    // staged row (chunk-lo), 0..63
    const int cofs = (lane & 3) << 3;         // halves within 32-wide k tile
    const _Float16* A1 = p.A1 + (size_t)row0 * K;
    const _Float16* A2 = p.A2 + (size_t)row0 * K;
    const _Float16* B1 = p.B1[z] + (size_t)col0 * K;
    const _Float16* B2 = p.B2[z] + (size_t)col0 * K;
    _Float16* sA1 = sm[0]; _Float16* sA2 = sm[1];
    _Float16* sB1 = sm[2]; _Float16* sB2 = sm[3];
    const int ldsLo = w * 512, ldsHi = (w + 4) * 512;

    v4f acc[4][4];
#pragma unroll
    for (int i = 0; i < 4; i++)
#pragma unroll
        for (int j = 0; j < 4; j++) acc[i][j] = (v4f){0.f, 0.f, 0.f, 0.f};

    for (int k0 = 0; k0 < K; k0 += 32) {
        __syncthreads();
        size_t glo = (size_t)rl * K + k0 + cofs;
        size_t ghi = glo + (size_t)64 * K;
        gl_lds16(A1 + glo, sA1 + ldsLo); gl_lds16(A1 + ghi, sA1 + ldsHi);
        gl_lds16(B1 + glo, sB1 + ldsLo); gl_lds16(B1 + ghi, sB1 + ldsHi);
        if (nt == 3) {
            gl_lds16(A2 + glo, sA2 + ldsLo); gl_lds16(A2 + ghi, sA2 + ldsHi);
            gl_lds16(B2 + glo, sB2 + ldsLo); gl_lds16(B2 + ghi, sB2 + ldsHi);
        }
        __syncthreads();
        v8h a1[4], b1f[4];
#pragma unroll
        for (int i = 0; i < 4; i++) {
            a1[i]  = *(const v8h*)(sA1 + (wm + (i << 4) + lm) * 32 + (kg << 3));
            b1f[i] = *(const v8h*)(sB1 + (wn + (i << 4) + lm) * 32 + (kg << 3));
        }
        if (nt == 3) {
            v8h a2[4], b2f[4];
#pragma unroll
            for (int i = 0; i < 4; i++) {
                a2[i]  = *(const v8h*)(sA2 + (wm + (i << 4) + lm) * 32 + (kg << 3));
                b2f[i] = *(const v8h*)(sB2 + (wn + (i << 4) + lm) * 32 + (kg << 3));
            }
#pragma unroll
            for (int i = 0; i < 4; i++)
#pragma unroll
                for (int j = 0; j < 4; j++) {
                    acc[i][j] = __builtin_amdgcn_mfma_f32_16x16x32_f16(a1[i], b1f[j], acc[i][j], 0, 0, 0);
                    acc[i][j] = __builtin_amdgcn_mfma_f32_16x16x32_f16(a1[i], b2f[j], acc[i][j], 0, 0, 0);
                    acc[i][j] = __builtin_amdgcn_mfma_f32_16x16x32_f16(a2[i], b1f[j], acc[i][j], 0, 0, 0);
                }
        } else {
#pragma unroll
            for (int i = 0; i < 4; i++)
#pragma unroll
                for (int j = 0; j < 4; j++)
                    acc[i][j] = __builtin_amdgcn_mfma_f32_16x16x32_f16(a1[i], b1f[j], acc[i][j], 0, 0, 0);
        }
    }
    float* C = p.C[z];
#pragma unroll
    for (int i = 0; i < 4; i++) {
        int rb = row0 + wm + (i << 4) + (kg << 2);
#pragma unroll
        for (int j = 0; j < 4; j++) {
            int cc = col0 + wn + (j << 4) + lm;
#pragma unroll
            for (int r = 0; r < 4; r++) {
                float c = acc[i][j][r] * cdiv;
                size_t idx = (size_t)(rb + r) * N + cc;
                if (epi == 0) {
                    C[idx] = c;
                } else {
                    float gv = gelu_f(c) * gscale;
                    _Float16 g1 = (_Float16)gv;
                    p.G1[idx] = g1;
                    p.G2[idx] = (_Float16)(gv - (float)g1);
                }
            }
        }
    }
}

// ---------------- fp32 -> 2-way fp16 split (Dekker), with power-of-2 scale ----------------
__global__ __launch_bounds__(256) void split2_kernel(const float* __restrict__ X,
    _Float16* __restrict__ A1, _Float16* __restrict__ A2, float s, int n)
{
    int i = (blockIdx.x * 256 + threadIdx.x) * 4;
    if (i >= n) return;
    float4 x = *(const float4*)(X + i);
    float v[4] = {x.x, x.y, x.z, x.w};
#pragma unroll
    for (int u = 0; u < 4; u++) {
        float xs = v[u] * s;
        _Float16 a = (_Float16)xs;
        A1[i + u] = a;
        A2[i + u] = (_Float16)(xs - (float)a);
    }
}

// ---------------- weight transpose + split: W[K,N] -> B1,B2 [N,K] (x64 scale) ----------------
__global__ __launch_bounds__(256) void wsplit_kernel(const float* __restrict__ W,
    _Float16* __restrict__ B1, _Float16* __restrict__ B2, int Kd, int N)
{
    int id = blockIdx.x * 256 + threadIdx.x;
    if (id >= Kd * N) return;
    int n = id / Kd, k = id - n * Kd;
    float v = W[(size_t)k * N + n] * 64.f;
    _Float16 b1 = (_Float16)v;
    B1[id] = b1;
    if (B2) B2[id] = (_Float16)(v - (float)b1);
}

// ---------------- prefix build + pooled attention mask ----------------
__global__ __launch_bounds__(256) void build_prefix_kernel(const int* __restrict__ sub,
    const float* __restrict__ mask, const float* __restrict__ amask,
    float* __restrict__ P, float* __restrict__ attn_out, int seq0)
{
    __shared__ float pref[64 * 64];
    int gl = blockIdx.x;
    int g = seq0 + gl;
    int tid = threadIdx.x;
    for (int t = tid; t < 4096; t += 256) pref[t] = 0.f;
    __syncthreads();
    if (tid < 64) {
        int r = sub[((size_t)g * 64 + tid) * 2 + 0];
        int c = sub[((size_t)g * 64 + tid) * 2 + 1];
        pref[(r << 6) + c] = 1.0f;
    }
    __syncthreads();
    float m = mask[g];
    int lane = tid & 63, w = tid >> 6;
    for (int s = (w << 4); s < (w << 4) + 16; s++) {
        float v = pref[(s << 6) + lane] * m;
        float rs = v;
#pragma unroll
        for (int o = 32; o; o >>= 1) rs += __shfl_down(rs, o);
        rs = __shfl(rs, 0);
        float nv = v / fmaxf(rs, 1e-12f);
        P[(((size_t)gl << 6) + s) * 64 + lane] = nv;
        float av = nv * amask[((size_t)g << 6) + lane];
#pragma unroll
        for (int o = 32; o; o >>= 1) av += __shfl_down(av, o);
        if (lane == 0) attn_out[((size_t)g << 6) + s] = av;
    }
}

// ---------------- subword->token embedding pooling ----------------
__global__ __launch_bounds__(256) void emb_pool_kernel(const float* __restrict__ P,
    const int* __restrict__ enc, const float* __restrict__ emb,
    float* __restrict__ X, int seq0)
{
    int s = blockIdx.x & 63;
    int gl = blockIdx.x >> 6;
    int g = seq0 + gl;
    int tid = threadIdx.x;
    __shared__ float pw[64];
    __shared__ int tk[64];
    if (tid < 64) {
        pw[tid] = P[(((size_t)gl << 6) + s) * 64 + tid];
        tk[tid] = enc[((size_t)g << 6) + tid];
    }
    __syncthreads();
    float a0 = 0.f, a1 = 0.f, a2 = 0.f;
    for (int t = 0; t < 64; t++) {
        float w = pw[t];
        if (w != 0.f) {
            const float* er = emb + (size_t)tk[t] * DIM;
            a0 = fmaf(w, er[tid], a0);
            a1 = fmaf(w, er[tid + 256], a1);
            a2 = fmaf(w, er[tid + 512], a2);
        }
    }
    size_t ro = (((size_t)gl << 6) + s) * DIM;
    X[ro + tid] = a0; X[ro + tid + 256] = a1; X[ro + tid + 512] = a2;
}

// ---------------- fused S=64 attention (fp32, exact-class; feeds kid path) ----------------
__global__ __launch_bounds__(256) void attn_fused64(const float* __restrict__ Q,
    const float* __restrict__ Km, const float* __restrict__ V,
    const float* __restrict__ mask, _Float16* __restrict__ o1, _Float16* __restrict__ o2)
{
    __shared__ float Ks[64 * 65];
    __shared__ float Vs[64 * 65];
    __shared__ float Qs[64 * 65];
    int h = blockIdx.x % NHEAD;
    int g = blockIdx.x / NHEAD;
    int tid = threadIdx.x, lane = tid & 63, w = tid >> 6;
    {
        int r = tid >> 2, c0 = (tid & 3) << 4;
        const float* qp = Q  + ((size_t)g * 64 + r) * DIM + h * DHEAD + c0;
        const float* kp = Km + ((size_t)g * 64 + r) * DIM + h * DHEAD + c0;
        const float* vp = V  + ((size_t)g * 64 + r) * DIM + h * DHEAD + c0;
#pragma unroll
        for (int u = 0; u < 16; u += 4) {
            float4 qv = *(const float4*)(qp + u);
            float4 kv = *(const float4*)(kp + u);
            float4 vv = *(const float4*)(vp + u);
            int o = r * 65 + c0 + u;
            Qs[o+0]=qv.x; Qs[o+1]=qv.y; Qs[o+2]=qv.z; Qs[o+3]=qv.w;
            Ks[o+0]=kv.x; Ks[o+1]=kv.y; Ks[o+2]=kv.z; Ks[o+3]=kv.w;
            Vs[o+0]=vv.x; Vs[o+1]=vv.y; Vs[o+2]=vv.z; Vs[o+3]=vv.w;
        }
    }
    __syncthreads();
    float mk = mask[(size_t)g * 64 + lane] > 0.f ? 0.f : -1e9f;
    for (int il = 0; il < 16; il++) {
        int i = (w << 4) + il;
        float d = 0.f;
        for (int t = 0; t < 64; t++) d = fmaf(Qs[i * 65 + t], Ks[lane * 65 + t], d);
        float l = d * 0.125f + mk;
        float mx = l;
#pragma unroll
        for (int o = 32; o; o >>= 1) mx = fmaxf(mx, __shfl_xor(mx, o));
        float e = expf(l - mx);
        float s = e;
#pragma unroll
        for (int o = 32; o; o >>= 1) s += __shfl_xor(s, o);
        float p = e / s;
        float acc = 0.f;
        for (int j = 0; j < 64; j++) {
            float pj = __shfl(p, j);
            acc = fmaf(pj, Vs[j * 65 + lane], acc);
        }
        size_t ob = ((size_t)g * 64 + i) * DIM + h * DHEAD + lane;
        float os = acc * 64.f;
        _Float16 h1 = (_Float16)os;
        o1[ob] = h1;
        o2[ob] = (_Float16)(os - (float)h1);
    }
}

// ---------------- MFMA flash attention S=400 (user BERT; feeds prob only, fp16 ok) -------
#define SSTR 449   // Sc row stride (f32): odd vs 32 banks -> conflict-free column scans
__global__ __launch_bounds__(256) void attn_flash400(const float* __restrict__ Q,
    const float* __restrict__ Km, const float* __restrict__ V,
    const float* __restrict__ mask, _Float16* __restrict__ o1, _Float16* __restrict__ o2)
{
    __shared__ _Float16 Kt[64 * 64];
    __shared__ float Sc[16 * SSTR];
    int qt = blockIdx.x % 25;
    int h  = (blockIdx.x / 25) % NHEAD;
    int g  = blockIdx.x / (25 * NHEAD);
    int tid = threadIdx.x, w = tid >> 6, lane = tid & 63, lm = lane & 15, kg = lane >> 4;

    v8h aq0, aq1;
    {
        const float* qp = Q + ((size_t)(g * 400 + qt * 16 + lm)) * DIM + h * DHEAD;
#pragma unroll
        for (int u = 0; u < 8; u++) {
            aq0[u] = (_Float16)qp[kg * 8 + u];
            aq1[u] = (_Float16)qp[32 + kg * 8 + u];
        }
    }
    for (int jt = 0; jt < 7; jt++) {
        int j0 = jt * 64;
        __syncthreads();
        {
            int jr = tid >> 2, c0 = (tid & 3) << 4;
            int j = j0 + jr;
            _Float16* kd = Kt + jr * 64 + c0;
            if (j < 400) {
                const float* kp = Km + ((size_t)(g * 400 + j)) * DIM + h * DHEAD + c0;
#pragma unroll
                for (int u = 0; u < 16; u++) kd[u] = (_Float16)kp[u];
            } else {
#pragma unroll
                for (int u = 0; u < 16; u++) kd[u] = (_Float16)0.f;
            }
        }
        __syncthreads();
        v8h b0, b1;
#pragma unroll
        for (int u = 0; u < 8; u++) {
            b0[u] = Kt[(w * 16 + lm) * 64 + kg * 8 + u];
            b1[u] = Kt[(w * 16 + lm) * 64 + 32 + kg * 8 + u];
        }
        v4f c = {0.f, 0.f, 0.f, 0.f};
        c = __builtin_amdgcn_mfma_f32_16x16x32_f16(aq0, b0, c, 0, 0, 0);
        c = __builtin_amdgcn_mfma_f32_16x16x32_f16(aq1, b1, c, 0, 0, 0);
        int jj = j0 + w * 16 + lm;
        float mv = (jj < 400) ? (mask[g * 400 + jj] > 0.f ? 0.f : -1e9f) : -1e9f;
#pragma unroll
        for (int r = 0; r < 4; r++)
            Sc[(kg * 4 + r) * SSTR + jj] = c[r] * 0.125f + mv;
    }
    __syncthreads();
    // softmax: wave w handles rows w*4..w*4+3; lane scans 7 strided cols
    for (int rr = 0; rr < 4; rr++) {
        int r = w * 4 + rr;
        float mx = -INFINITY;
#pragma unroll
        for (int c7 = 0; c7 < 7; c7++) mx = fmaxf(mx, Sc[r * SSTR + c7 * 64 + lane]);
#pragma unroll
        for (int o = 32; o; o >>= 1) mx = fmaxf(mx, __shfl_xor(mx, o));
        float s = 0.f;
        float ev[7];
#pragma unroll
        for (int c7 = 0; c7 < 7; c7++) { ev[c7] = expf(Sc[r * SSTR + c7 * 64 + lane] - mx); s += ev[c7]; }
#pragma unroll
        for (int o = 32; o; o >>= 1) s += __shfl_xor(s, o);
        float inv = 1.f / s;
#pragma unroll
        for (int c7 = 0; c7 < 7; c7++) Sc[r * SSTR + c7 * 64 + lane] = ev[c7] * inv;
    }
    __syncthreads();
    // PV: wave w owns d-tile w*16; A = P (LDS f32->f16), B = V^T direct from global
    v4f o = {0.f, 0.f, 0.f, 0.f};
    for (int kc = 0; kc < 14; kc++) {
        v8h a, b;
#pragma unroll
        for (int u = 0; u < 8; u++) a[u] = (_Float16)Sc[lm * SSTR + kc * 32 + kg * 8 + u];
#pragma unroll
        for (int u = 0; u < 8; u++) {
            int j = kc * 32 + kg * 8 + u;
            b[u] = (j < 400) ? (_Float16)V[((size_t)(g * 400 + j)) * DIM + h * DHEAD + w * 16 + lm]
                             : (_Float16)0.f;
        }
        o = __builtin_amdgcn_mfma_f32_16x16x32_f16(a, b, o, 0, 0, 0);
    }
#pragma unroll
    for (int r = 0; r < 4; r++) {
        int qr = qt * 16 + kg * 4 + r;
        size_t ob = ((size_t)(g * 400 + qr)) * DIM + h * DHEAD + w * 16 + lm;
        float os = o[r] * 64.f;
        _Float16 h1 = (_Float16)os;
        o1[ob] = h1; o2[ob] = (_Float16)(os - (float)h1);
    }
}

// ---------------- h = LayerNorm(X + Y) ----------------
__global__ __launch_bounds__(256) void add_ln_kernel(const float* __restrict__ X,
    const float* __restrict__ Y, float* __restrict__ Out)
{
    int r = blockIdx.x, tid = threadIdx.x;
    size_t base = (size_t)r * DIM;
    float v0 = X[base + tid] + Y[base + tid];
    float v1 = X[base + tid + 256] + Y[base + tid + 256];
    float v2 = X[base + tid + 512] + Y[base + tid + 512];
    __shared__ float red[256];
    red[tid] = v0 + v1 + v2; __syncthreads();
    for (int o = 128; o; o >>= 1) { if (tid < o) red[tid] += red[tid + o]; __syncthreads(); }
    float mu = red[0] * (1.f / 768.f);
    __syncthreads();
    float d0 = v0 - mu, d1 = v1 - mu, d2 = v2 - mu;
    red[tid] = d0 * d0 + d1 * d1 + d2 * d2; __syncthreads();
    for (int o = 128; o; o >>= 1) { if (tid < o) red[tid] += red[tid + o]; __syncthreads(); }
    float rstd = rsqrtf(red[0] * (1.f / 768.f) + 1e-12f);
    Out[base + tid] = d0 * rstd;
    Out[base + tid + 256] = d1 * rstd;
    Out[base + tid + 512] = d2 * rstd;
}

__global__ void cls_copy_kernel(const float* __restrict__ H, float* __restrict__ cls, int S) {
    int g = blockIdx.x, tid = threadIdx.x;
    size_t src = (size_t)g * S * DIM;
    cls[(size_t)g * DIM + tid]       = H[src + tid];
    cls[(size_t)g * DIM + tid + 256] = H[src + tid + 256];
    cls[(size_t)g * DIM + tid + 512] = H[src + tid + 512];
}

// ---------------- legacy fp32 SIMT GEMM (tiny proj GEMMs only) ----------------
__global__ __launch_bounds__(256) void gemm_kernel(const float* __restrict__ A,
    const float* __restrict__ B, float* __restrict__ C,
    int M, int N, int Kd, int epi, const float* __restrict__ bias)
{
    __shared__ float As[16][64];
    __shared__ float Bs[16][64];
    int tid = threadIdx.x;
    int tx = tid & 15, ty = tid >> 4;
    int row0 = blockIdx.y << 6, col0 = blockIdx.x << 6;
    int ar = tid >> 2, ak = (tid & 3) << 2;
    int bc = tid & 63, bk0 = tid >> 6;
    const float* Ap = A + (size_t)(row0 + ar) * Kd + ak;
    const float* Bp = B + (size_t)bk0 * N + col0 + bc;
    bool aval = (row0 + ar) < M;
    float acc[4][4];
#pragma unroll
    for (int i = 0; i < 4; i++)
#pragma unroll
        for (int j = 0; j < 4; j++) acc[i][j] = 0.f;
    for (int k0 = 0; k0 < Kd; k0 += 16) {
        float4 a4 = make_float4(0.f, 0.f, 0.f, 0.f);
        if (aval) a4 = *(const float4*)(Ap + k0);
        As[ak + 0][ar] = a4.x; As[ak + 1][ar] = a4.y;
        As[ak + 2][ar] = a4.z; As[ak + 3][ar] = a4.w;
#pragma unroll
        for (int i = 0; i < 4; i++)
            Bs[bk0 + 4 * i][bc] = Bp[(size_t)(k0 + 4 * i) * N];
        __syncthreads();
#pragma unroll
        for (int kk = 0; kk < 16; kk++) {
            float4 av = *(const float4*)&As[kk][ty << 2];
            float4 bv = *(const float4*)&Bs[kk][tx << 2];
            float aa[4] = {av.x, av.y, av.z, av.w};
            float bb[4] = {bv.x, bv.y, bv.z, bv.w};
#pragma unroll
            for (int i = 0; i < 4; i++)
#pragma unroll
                for (int j = 0; j < 4; j++)
                    acc[i][j] = fmaf(aa[i], bb[j], acc[i][j]);
        }
        __syncthreads();
    }
#pragma unroll
    for (int i = 0; i < 4; i++) {
        int r = row0 + (ty << 2) + i;
        if (r >= M) continue;
        float v[4];
#pragma unroll
        for (int j = 0; j < 4; j++) {
            float x = acc[i][j];
            if (epi == 1) x = gelu_f(x);
            else if (epi == 2) x = tanhf(x + bias[col0 + (tx << 2) + j]);
            v[j] = x;
        }
        *(float4*)(C + (size_t)r * N + col0 + (tx << 2)) = make_float4(v[0], v[1], v[2], v[3]);
    }
}

// ---------------- user attention pooling ----------------
__global__ __launch_bounds__(256) void user_pool_kernel(const float* __restrict__ cls,
    const float* __restrict__ qU, float* __restrict__ user0)
{
    int b = blockIdx.x, tid = threadIdx.x;
    __shared__ float red[256];
    __shared__ float wv[64];
    const float scale = 0.03608439182435161f;
    for (int n = 0; n < 50; n++) {
        const float* cr = cls + ((size_t)(b * 50 + n)) * DIM;
        float d = 0.f;
        for (int t = tid; t < DIM; t += 256) d = fmaf(cr[t], qU[t], d);
        red[tid] = d; __syncthreads();
        for (int o = 128; o; o >>= 1) { if (tid < o) red[tid] += red[tid + o]; __syncthreads(); }
        if (tid == 0) wv[n] = red[0] * scale;
        __syncthreads();
    }
    if (tid == 0) {
        float mx = -INFINITY;
        for (int n = 0; n < 50; n++) mx = fmaxf(mx, wv[n]);
        float s = 0.f;
        for (int n = 0; n < 50; n++) { float e = expf(wv[n] - mx); wv[n] = e; s += e; }
        float inv = 1.f / s;
        for (int n = 0; n < 50; n++) wv[n] *= inv;
    }
    __syncthreads();
    for (int d = tid; d < DIM; d += 256) {
        float a = 0.f;
        for (int n = 0; n < 50; n++) a = fmaf(wv[n], cls[((size_t)(b * 50 + n)) * DIM + d], a);
        user0[(size_t)b * DIM + d] = a;
    }
}

// ---------------- personalized-term scores + stable top-8 ----------------
__global__ __launch_bounds__(256) void topk_kernel(const float* __restrict__ hid,
    const float* __restrict__ user0, const float* __restrict__ attn,
    float* __restrict__ kid_f, int* __restrict__ kid_i, float* __restrict__ ps_mask)
{
    int bn = blockIdx.x;
    int b = bn / 50;
    int tid = threadIdx.x, lane = tid & 63, w = tid >> 6;
    __shared__ float sc[64];
    const float* u = user0 + (size_t)b * DIM;
    const float scale = 0.03608439182435161f;
    for (int s = w; s < 64; s += 4) {
        const float* hr = hid + ((size_t)bn * 64 + s) * DIM;
        float d = 0.f;
        for (int t = lane; t < DIM; t += 64) d = fmaf(hr[t], u[t], d);
#pragma unroll
        for (int o = 32; o; o >>= 1) d += __shfl_down(d, o);
        if (lane == 0) {
            float a = attn[(size_t)bn * 64 + s];
            sc[s] = (a > 0.f) ? d * scale : -1e9f;
        }
    }
    __syncthreads();
    if (tid == 0) {
        unsigned long long used = 0ull;
        for (int k = 0; k < 8; k++) {
            float best = -INFINITY; int bi = 0;
            for (int s = 0; s < 64; s++) {
                if ((used >> s) & 1ull) continue;
                if (sc[s] > best) { best = sc[s]; bi = s; }
            }
            used |= (1ull << bi);
            kid_i[bn * 8 + k] = bi;
            kid_f[bn * 8 + k] = (float)bi;
            ps_mask[bn * 8 + k] = attn[(size_t)bn * 64 + bi];
        }
    }
}

__global__ void gather_kernel(const float* __restrict__ hid, const int* __restrict__ kid_i,
    float* __restrict__ X)
{
    int r = blockIdx.x, tid = threadIdx.x;
    int s = kid_i[r];
    int bn = r >> 3;
    const float* src = hid + ((size_t)bn * 64 + s) * DIM;
    float* dst = X + (size_t)r * DIM;
    dst[tid] = src[tid];
    dst[tid + 256] = src[tid + 256];
    dst[tid + 512] = src[tid + 512];
}

__global__ __launch_bounds__(256) void final_kernel(const float* __restrict__ cdd_repr,
    const float* __restrict__ user_repr, float* __restrict__ out)
{
    int b = blockIdx.x, tid = threadIdx.x;
    __shared__ float red[256];
    __shared__ float sc[5];
    const float scale = 0.03608439182435161f;
    for (int c = 0; c < 5; c++) {
        const float* cr = cdd_repr + ((size_t)(b * 5 + c)) * DIM;
        const float* ur = user_repr + (size_t)b * DIM;
        float d = 0.f;
        for (int t = tid; t < DIM; t += 256) d = fmaf(cr[t], ur[t], d);
        red[tid] = d; __syncthreads();
        for (int o = 128; o; o >>= 1) { if (tid < o) red[tid] += red[tid + o]; __syncthreads(); }
        if (tid == 0) sc[c] = red[0] * scale;
        __syncthreads();
    }
    if (tid == 0) {
        float mx = -INFINITY;
        for (int c = 0; c < 5; c++) mx = fmaxf(mx, sc[c]);
        float s = 0.f;
        for (int c = 0; c < 5; c++) s += expf(sc[c] - mx);
        float lse = logf(s) + mx;
        for (int c = 0; c < 5; c++) out[b * 5 + c] = sc[c] - lse;
    }
}

extern "C" void kernel_launch(void* const* d_in, const int* in_sizes, int n_in,
                              void* d_out, int out_size, void* d_ws, size_t ws_size,
                              hipStream_t stream)
{
    (void)in_sizes; (void)n_in; (void)out_size;
    const int*   cdd_sub   = (const int*)d_in[0];
    const int*   his_sub   = (const int*)d_in[1];
    const int*   cdd_enc   = (const int*)d_in[2];
    const int*   his_enc   = (const int*)d_in[3];
    const float* cdd_mask  = (const float*)d_in[4];
    const float* his_mask  = (const float*)d_in[5];
    const float* cdd_amask = (const float*)d_in[6];
    const float* his_amask = (const float*)d_in[7];
    const float* emb = (const float*)d_in[8];
    const float* bWsrc[6] = {(const float*)d_in[9],  (const float*)d_in[10], (const float*)d_in[11],
                             (const float*)d_in[12], (const float*)d_in[13], (const float*)d_in[14]};
    const float* eWsrc[6] = {(const float*)d_in[15], (const float*)d_in[16], (const float*)d_in[17],
                             (const float*)d_in[18], (const float*)d_in[19], (const float*)d_in[20]};
    const float* qU = (const float*)d_in[21];
    const float* pW = (const float*)d_in[22];
    const float* pb = (const float*)d_in[23];
    float* out = (float*)d_out;

    // ---- dynamic chunk size: largest CH with dyn(CH)+fixed <= ws_size ----
    // dyn bytes = RC*21760 (RC = CH*64); fixed ~= 122.8 MB (hisH + weights + small)
    const size_t FIXED = 124ull * 1000 * 1000;
    int CH = 50;
    {
        int opts[4] = {400, 200, 100, 50};
        for (int i = 0; i < 4; i++) {
            size_t need = FIXED + (size_t)opts[i] * 64 * 21760;
            if (need <= ws_size) { CH = opts[i]; break; }
        }
    }
    const size_t RC = (size_t)CH * 64;

    // ---- workspace carve (bytes, 256-aligned; R_K,R_V contiguous for g1h alias) ----
    char* wsb = (char*)d_ws;
    size_t off = 0;
    auto allocB = [&](size_t bytes) { char* p = wsb + off; off += (bytes + 255) & ~(size_t)255; return p; };
    float* R_X = (float*)allocB(RC * 768 * 4);
    float* R_Q = (float*)allocB(RC * 768 * 4);
    float* R_K = (float*)allocB(RC * 768 * 4);   // g1h aliases K+V during FFN
    float* R_V = (float*)allocB(RC * 768 * 4);
    _Float16* s1h = (_Float16*)allocB(RC * 768 * 2);
    _Float16* s2h = (_Float16*)allocB(RC * 768 * 2);
    _Float16* g2h = (_Float16*)allocB(RC * 3072 * 2);
    float* R_Pa = (float*)allocB((size_t)CH * 4096 * 4);
    float* hisH  = (float*)allocB((size_t)400 * 64 * 768 * 4);
    float* hisC  = (float*)allocB((size_t)400 * 768 * 4);
    float* cddC  = (float*)allocB((size_t)40 * 768 * 4);
    float* userC = (float*)allocB((size_t)8 * 768 * 4);
    float* hisA  = (float*)allocB((size_t)400 * 64 * 4);
    float* cddA  = (float*)allocB((size_t)40 * 64 * 4);
    float* cddR  = (float*)allocB((size_t)40 * 768 * 4);
    float* userR = (float*)allocB((size_t)8 * 768 * 4);
    float* user0 = (float*)allocB((size_t)8 * 768 * 4);
    float* psM   = (float*)allocB((size_t)8 * 400 * 4);
    int*   kidI  = (int*)allocB(3200 * 4);
    size_t wsz[6] = {589824, 589824, 589824, 589824, 2359296, 2359296};
    _Float16 *eB1[6], *eB2[6], *bB1[6];
    for (int i = 0; i < 6; i++) eB1[i] = (_Float16*)allocB(wsz[i] * 2);
    for (int i = 0; i < 6; i++) eB2[i] = (_Float16*)allocB(wsz[i] * 2);
    for (int i = 0; i < 6; i++) bB1[i] = (_Float16*)allocB(wsz[i] * 2);
    _Float16* g1h = (_Float16*)R_K;   // RC*3072 halves over K+V

    // ---- weight transpose+split (x64 scale) ----
    int wk[6] = {768, 768, 768, 768, 768, 3072};
    int wn[6] = {768, 768, 768, 768, 3072, 768};
    for (int i = 0; i < 6; i++) {
        int n = wk[i] * wn[i];
        wsplit_kernel<<<(n + 255) / 256, 256, 0, stream>>>(eWsrc[i], eB1[i], eB2[i], wk[i], wn[i]);
        wsplit_kernel<<<(n + 255) / 256, 256, 0, stream>>>(bWsrc[i], bB1[i], nullptr, wk[i], wn[i]);
    }

    // ---- one transformer pass over R_X (R rows = nseq*S) ----
    auto tf = [&](const float* maskp, int nseq, int S, _Float16* const* B1, _Float16* const* B2,
                  int nt, float* outH, float* clsD) {
        int R = nseq * S, MB = R >> 7;
        int nsplit = (R * 768 / 4 + 255) / 256;
        split2_kernel<<<nsplit, 256, 0, stream>>>(R_X, s1h, s2h, 64.f, R * 768);
        GemmP gq{};
        gq.A1 = s1h; gq.A2 = s2h;
        for (int z = 0; z < 3; z++) { gq.B1[z] = B1[z]; gq.B2[z] = B2 ? B2[z] : B1[z]; }
        gq.C[0] = R_Q; gq.C[1] = R_K; gq.C[2] = R_V;
        gemm_mfma<<<dim3(6, MB, 3), 256, 0, stream>>>(gq, R, 768, 768, nt, 0, 1.f / 4096.f, 0.f);
        if (S == 64) {
            attn_fused64<<<nseq * NHEAD, 256, 0, stream>>>(R_Q, R_K, R_V, maskp, s1h, s2h);
        } else {
            attn_flash400<<<8 * NHEAD * 25, 256, 0, stream>>>(R_Q, R_K, R_V, maskp, s1h, s2h);
        }
        GemmP go{};
        go.A1 = s1h; go.A2 = s2h;
        go.B1[0] = B1[3]; go.B2[0] = B2 ? B2[3] : B1[3];
        go.C[0] = R_Q;
        gemm_mfma<<<dim3(6, MB, 1), 256, 0, stream>>>(go, R, 768, 768, nt, 0, 1.f / 4096.f, 0.f);
        add_ln_kernel<<<R, 256, 0, stream>>>(R_X, R_Q, R_X);
        split2_kernel<<<nsplit, 256, 0, stream>>>(R_X, s1h, s2h, 1.f, R * 768);
        GemmP g1{};
        g1.A1 = s1h; g1.A2 = s2h;
        g1.B1[0] = B1[4]; g1.B2[0] = B2 ? B2[4] : B1[4];
        g1.G1 = g1h; g1.G2 = g2h; g1.C[0] = nullptr;
        gemm_mfma<<<dim3(24, MB, 1), 256, 0, stream>>>(g1, R, 3072, 768, nt, 1, 1.f / 64.f, 16.f);
        GemmP g2{};
        g2.A1 = g1h; g2.A2 = g2h;
        g2.B1[0] = B1[5]; g2.B2[0] = B2 ? B2[5] : B1[5];
        g2.C[0] = R_Q;
        gemm_mfma<<<dim3(6, MB, 1), 256, 0, stream>>>(g2, R, 768, 3072, nt, 0, 1.f / 1024.f, 0.f);
        add_ln_kernel<<<R, 256, 0, stream>>>(R_X, R_Q, outH);
        cls_copy_kernel<<<nseq, 256, 0, stream>>>(outH, clsD, S);
    };

    // ---- candidate news (bert, nt=1 fp16) ----
    build_prefix_kernel<<<40, 256, 0, stream>>>(cdd_sub, cdd_mask, cdd_amask, R_Pa, cddA, 0);
    emb_pool_kernel<<<40 * 64, 256, 0, stream>>>(R_Pa, cdd_enc, emb, R_X, 0);
    tf(cddA, 40, 64, bB1, nullptr, 1, R_X, cddC);
    gemm_kernel<<<dim3(12, 1), 256, 0, stream>>>(cddC, pW, cddR, 40, 768, 768, 2, pb);

    // ---- history news (encN, nt=3 split ~ fp32 accurate), dynamic chunks ----
    for (int seq0 = 0; seq0 < 400; seq0 += CH) {
        build_prefix_kernel<<<CH, 256, 0, stream>>>(his_sub, his_mask, his_amask, R_Pa, hisA, seq0);
        emb_pool_kernel<<<CH * 64, 256, 0, stream>>>(R_Pa, his_enc, emb, R_X, seq0);
        tf(hisA + (size_t)seq0 * 64, CH, 64, eB1, eB2, 3,
           hisH + (size_t)seq0 * 64 * DIM, hisC + (size_t)seq0 * DIM);
    }

    // ---- user encoder + matching reducer (fp32) ----
    user_pool_kernel<<<8, 256, 0, stream>>>(hisC, qU, user0);
    topk_kernel<<<400, 256, 0, stream>>>(hisH, user0, hisA, out + 40, kidI, psM);
    gather_kernel<<<3200, 256, 0, stream>>>(hisH, kidI, R_X);

    // ---- user BERT over selected terms (bert, nt=1; MFMA flash attention) ----
    tf(psM, 8, 400, bB1, nullptr, 1, R_X, userC);
    gemm_kernel<<<dim3(12, 1), 256, 0, stream>>>(userC, pW, userR, 8, 768, 768, 2, pb);

    final_kernel<<<8, 256, 0, stream>>>(cddR, userR, out);
}

// Round 5
// 3215.620 us; speedup vs baseline: 3.8054x; 1.1287x over previous
//
#include <hip/hip_runtime.h>
#include <math.h>

#define DIM 768
#define NHEAD 12
#define DHEAD 64
#define FFDIM 3072

typedef _Float16 v8h __attribute__((ext_vector_type(8)));
typedef float v4f __attribute__((ext_vector_type(4)));

__device__ __forceinline__ float gelu_f(float x) {
    float x3 = x * x * x;
    return 0.5f * x * (1.0f + tanhf(0.7978845608028654f * (x + 0.044715f * x3)));
}

// async global->LDS, 16B per lane; lds base must be wave-uniform (HW adds lane*16)
__device__ __forceinline__ void gl_lds16(const _Float16* g, _Float16* l) {
    __builtin_amdgcn_global_load_lds(
        (const __attribute__((address_space(1))) unsigned int*)(g),
        (__attribute__((address_space(3))) unsigned int*)(l),
        16, 0, 0);
}

// ================= MFMA GEMM: per-block weight set ===============================
// rows < bnd: encN weights, nt=3 (A1B1+A1B2+A2B1); rows >= bnd: bert weights, nt=1.
struct GemmP {
    const _Float16* A1; const _Float16* A2;
    const _Float16* eB1[3]; const _Float16* eB2[3]; const _Float16* bB1[3];
    float* C[3];
    _Float16* G1; _Float16* G2;
    int bnd;
};

__global__ __launch_bounds__(256) void gemm_mfma(GemmP p, int M, int N, int K,
                                                 int epi, float cdiv, float gscale)
{
    __shared__ _Float16 sm[4][128 * 32];
    const int z = blockIdx.z;
    const int tid = threadIdx.x;
    const int w = tid >> 6, lane = tid & 63;
    const int lm = lane & 15, kg = lane >> 4;
    const int row0 = blockIdx.y << 7, col0 = blockIdx.x << 7;
    const int wm = (w >> 1) << 6, wn = (w & 1) << 6;
    const int rl = (w << 4) + (lane >> 2);
    const int cofs = (lane & 3) << 3;
    int nt; const _Float16 *B1p, *B2p;
    if (row0 < p.bnd) { nt = 3; B1p = p.eB1[z]; B2p = p.eB2[z]; }
    else             { nt = 1; B1p = p.bB1[z]; B2p = p.bB1[z]; }
    const _Float16* A1 = p.A1 + (size_t)row0 * K;
    const _Float16* A2 = p.A2 + (size_t)row0 * K;
    const _Float16* B1 = B1p + (size_t)col0 * K;
    const _Float16* B2 = B2p + (size_t)col0 * K;
    _Float16* sA1 = sm[0]; _Float16* sA2 = sm[1];
    _Float16* sB1 = sm[2]; _Float16* sB2 = sm[3];
    const int ldsLo = w * 512, ldsHi = (w + 4) * 512;

    v4f acc[4][4];
#pragma unroll
    for (int i = 0; i < 4; i++)
#pragma unroll
        for (int j = 0; j < 4; j++) acc[i][j] = (v4f){0.f, 0.f, 0.f, 0.f};

    for (int k0 = 0; k0 < K; k0 += 32) {
        __syncthreads();
        size_t glo = (size_t)rl * K + k0 + cofs;
        size_t ghi = glo + (size_t)64 * K;
        gl_lds16(A1 + glo, sA1 + ldsLo); gl_lds16(A1 + ghi, sA1 + ldsHi);
        gl_lds16(B1 + glo, sB1 + ldsLo); gl_lds16(B1 + ghi, sB1 + ldsHi);
        if (nt == 3) {
            gl_lds16(A2 + glo, sA2 + ldsLo); gl_lds16(A2 + ghi, sA2 + ldsHi);
            gl_lds16(B2 + glo, sB2 + ldsLo); gl_lds16(B2 + ghi, sB2 + ldsHi);
        }
        __syncthreads();
        v8h a1[4], b1f[4];
#pragma unroll
        for (int i = 0; i < 4; i++) {
            a1[i]  = *(const v8h*)(sA1 + (wm + (i << 4) + lm) * 32 + (kg << 3));
            b1f[i] = *(const v8h*)(sB1 + (wn + (i << 4) + lm) * 32 + (kg << 3));
        }
        if (nt == 3) {
            v8h a2[4], b2f[4];
#pragma unroll
            for (int i = 0; i < 4; i++) {
                a2[i]  = *(const v8h*)(sA2 + (wm + (i << 4) + lm) * 32 + (kg << 3));
                b2f[i] = *(const v8h*)(sB2 + (wn + (i << 4) + lm) * 32 + (kg << 3));
            }
#pragma unroll
            for (int i = 0; i < 4; i++)
#pragma unroll
                for (int j = 0; j < 4; j++) {
                    acc[i][j] = __builtin_amdgcn_mfma_f32_16x16x32_f16(a1[i], b1f[j], acc[i][j], 0, 0, 0);
                    acc[i][j] = __builtin_amdgcn_mfma_f32_16x16x32_f16(a1[i], b2f[j], acc[i][j], 0, 0, 0);
                    acc[i][j] = __builtin_amdgcn_mfma_f32_16x16x32_f16(a2[i], b1f[j], acc[i][j], 0, 0, 0);
                }
        } else {
#pragma unroll
            for (int i = 0; i < 4; i++)
#pragma unroll
                for (int j = 0; j < 4; j++)
                    acc[i][j] = __builtin_amdgcn_mfma_f32_16x16x32_f16(a1[i], b1f[j], acc[i][j], 0, 0, 0);
        }
    }
    float* C = p.C[z];
#pragma unroll
    for (int i = 0; i < 4; i++) {
        int rb = row0 + wm + (i << 4) + (kg << 2);
#pragma unroll
        for (int j = 0; j < 4; j++) {
            int cc = col0 + wn + (j << 4) + lm;
#pragma unroll
            for (int r = 0; r < 4; r++) {
                float c = acc[i][j][r] * cdiv;
                size_t idx = (size_t)(rb + r) * N + cc;
                if (epi == 0) {
                    C[idx] = c;
                } else {
                    float gv = gelu_f(c) * gscale;
                    _Float16 g1 = (_Float16)gv;
                    p.G1[idx] = g1;
                    p.G2[idx] = (_Float16)(gv - (float)g1);
                }
            }
        }
    }
}

// ---------------- single-launch tiled weight transpose + split (x64) ----------------
struct WJobs {
    const float* src[12];
    _Float16* d1[12]; _Float16* d2[12];
    int K[12]; int N[12]; int start[12];
};
__global__ __launch_bounds__(256) void wsplit_tr(WJobs jb)
{
    __shared__ float sh[32 * 33];
    int bid = blockIdx.x;
    int ji = 0;
#pragma unroll
    for (int i = 1; i < 12; i++) if (bid >= jb.start[i]) ji = i;
    const float* src = jb.src[ji];
    _Float16* d1 = jb.d1[ji]; _Float16* d2 = jb.d2[ji];
    int K = jb.K[ji], N = jb.N[ji];
    int t = bid - jb.start[ji];
    int tilesN = N >> 5;
    int tk = t / tilesN, tn = t - tk * tilesN;
    int k0 = tk << 5, n0 = tn << 5;
    int c = threadIdx.x & 31, rr = threadIdx.x >> 5;
#pragma unroll
    for (int pph = 0; pph < 4; pph++) {
        int r = rr + (pph << 3);
        sh[c * 33 + r] = src[(size_t)(k0 + r) * N + n0 + c];
    }
    __syncthreads();
#pragma unroll
    for (int pph = 0; pph < 4; pph++) {
        int rn = rr + (pph << 3);
        float v = sh[rn * 33 + c] * 64.f;
        _Float16 b1 = (_Float16)v;
        size_t idx = (size_t)(n0 + rn) * K + k0 + c;
        d1[idx] = b1;
        if (d2) d2[idx] = (_Float16)(v - (float)b1);
    }
}

// ---------------- prefix build + pooled attention mask (his + cdd batched) ----------
__global__ __launch_bounds__(256) void build_prefix2(const int* __restrict__ hisSub,
    const float* __restrict__ hisMask, const float* __restrict__ hisAmask,
    const int* __restrict__ cddSub, const float* __restrict__ cddMask,
    const float* __restrict__ cddAmask,
    float* __restrict__ P, float* __restrict__ hisA, float* __restrict__ cddA)
{
    __shared__ float pref[64 * 64];
    int g = blockIdx.x;
    const int* sub; const float* mask; const float* amask; float* aout; int li;
    if (g < 400) { sub = hisSub; mask = hisMask; amask = hisAmask; aout = hisA; li = g; }
    else         { sub = cddSub; mask = cddMask; amask = cddAmask; aout = cddA; li = g - 400; }
    int tid = threadIdx.x;
    for (int t = tid; t < 4096; t += 256) pref[t] = 0.f;
    __syncthreads();
    if (tid < 64) {
        int r = sub[((size_t)li * 64 + tid) * 2 + 0];
        int c = sub[((size_t)li * 64 + tid) * 2 + 1];
        pref[(r << 6) + c] = 1.0f;
    }
    __syncthreads();
    float m = mask[li];
    int lane = tid & 63, w = tid >> 6;
    for (int s = (w << 4); s < (w << 4) + 16; s++) {
        float v = pref[(s << 6) + lane] * m;
        float rs = v;
#pragma unroll
        for (int o = 32; o; o >>= 1) rs += __shfl_down(rs, o);
        rs = __shfl(rs, 0);
        float nv = v / fmaxf(rs, 1e-12f);
        P[(((size_t)g << 6) + s) * 64 + lane] = nv;
        float av = nv * amask[((size_t)li << 6) + lane];
#pragma unroll
        for (int o = 32; o; o >>= 1) av += __shfl_down(av, o);
        if (lane == 0) aout[((size_t)li << 6) + s] = av;
    }
}

// ---------------- subword->token pooling, 16 rows/block, fused x64 split ------------
__global__ __launch_bounds__(256) void emb_pool2(const float* __restrict__ P,
    const int* __restrict__ encHis, const int* __restrict__ encCdd,
    const float* __restrict__ emb, float* __restrict__ X,
    _Float16* __restrict__ s1, _Float16* __restrict__ s2, int gOffHis, int gMid)
{
    int gl = blockIdx.x >> 2, q = blockIdx.x & 3;
    int g; const int* enc;
    if (gl < gMid) { g = gOffHis + gl; enc = encHis + (size_t)g * 64; }
    else { int gc = gl - gMid; g = 400 + gc; enc = encCdd + (size_t)gc * 64; }
    int tid = threadIdx.x;
    __shared__ float pw[16][64];
    __shared__ int tk[64];
    if (tid < 64) tk[tid] = enc[tid];
    for (int u = tid; u < 1024; u += 256) {
        int si = u >> 6, t = u & 63;
        pw[si][t] = P[((size_t)g * 64 + q * 16 + si) * 64 + t];
    }
    __syncthreads();
    float acc[16][3];
#pragma unroll
    for (int si = 0; si < 16; si++) { acc[si][0] = 0.f; acc[si][1] = 0.f; acc[si][2] = 0.f; }
    for (int t = 0; t < 64; t++) {
        const float* er = emb + (size_t)tk[t] * DIM;
        float e0 = er[tid], e1 = er[tid + 256], e2 = er[tid + 512];
#pragma unroll
        for (int si = 0; si < 16; si++) {
            float w = pw[si][t];
            acc[si][0] = fmaf(w, e0, acc[si][0]);
            acc[si][1] = fmaf(w, e1, acc[si][1]);
            acc[si][2] = fmaf(w, e2, acc[si][2]);
        }
    }
#pragma unroll
    for (int si = 0; si < 16; si++) {
        size_t base = ((size_t)gl * 64 + q * 16 + si) * DIM;
#pragma unroll
        for (int cci = 0; cci < 3; cci++) {
            int cc = tid + (cci << 8);
            float v = acc[si][cci];
            X[base + cc] = v;
            float xs = v * 64.f;
            _Float16 a = (_Float16)xs;
            s1[base + cc] = a;
            s2[base + cc] = (_Float16)(xs - (float)a);
        }
    }
}

// ---------------- fused S=64 attention (fp32 exact-class), batched masks ------------
__global__ __launch_bounds__(256) void attn_fused64(const float* __restrict__ Q,
    const float* __restrict__ Km, const float* __restrict__ V,
    const float* __restrict__ maskHis, const float* __restrict__ maskCdd, int gMid,
    _Float16* __restrict__ o1, _Float16* __restrict__ o2)
{
    __shared__ float Ks[64 * 65];
    __shared__ float Vs[64 * 65];
    __shared__ float Qs[64 * 65];
    int h = blockIdx.x % NHEAD;
    int g = blockIdx.x / NHEAD;
    const float* mrow = (g < gMid) ? maskHis + (size_t)g * 64
                                   : maskCdd + (size_t)(g - gMid) * 64;
    int tid = threadIdx.x, lane = tid & 63, w = tid >> 6;
    {
        int r = tid >> 2, c0 = (tid & 3) << 4;
        const float* qp = Q  + ((size_t)g * 64 + r) * DIM + h * DHEAD + c0;
        const float* kp = Km + ((size_t)g * 64 + r) * DIM + h * DHEAD + c0;
        const float* vp = V  + ((size_t)g * 64 + r) * DIM + h * DHEAD + c0;
#pragma unroll
        for (int u = 0; u < 16; u += 4) {
            float4 qv = *(const float4*)(qp + u);
            float4 kv = *(const float4*)(kp + u);
            float4 vv = *(const float4*)(vp + u);
            int o = r * 65 + c0 + u;
            Qs[o+0]=qv.x; Qs[o+1]=qv.y; Qs[o+2]=qv.z; Qs[o+3]=qv.w;
            Ks[o+0]=kv.x; Ks[o+1]=kv.y; Ks[o+2]=kv.z; Ks[o+3]=kv.w;
            Vs[o+0]=vv.x; Vs[o+1]=vv.y; Vs[o+2]=vv.z; Vs[o+3]=vv.w;
        }
    }
    __syncthreads();
    float mk = mrow[lane] > 0.f ? 0.f : -1e9f;
    for (int il = 0; il < 16; il++) {
        int i = (w << 4) + il;
        float d = 0.f;
        for (int t = 0; t < 64; t++) d = fmaf(Qs[i * 65 + t], Ks[lane * 65 + t], d);
        float l = d * 0.125f + mk;
        float mx = l;
#pragma unroll
        for (int o = 32; o; o >>= 1) mx = fmaxf(mx, __shfl_xor(mx, o));
        float e = expf(l - mx);
        float s = e;
#pragma unroll
        for (int o = 32; o; o >>= 1) s += __shfl_xor(s, o);
        float p = e / s;
        float acc = 0.f;
        for (int j = 0; j < 64; j++) {
            float pj = __shfl(p, j);
            acc = fmaf(pj, Vs[j * 65 + lane], acc);
        }
        size_t ob = ((size_t)g * 64 + i) * DIM + h * DHEAD + lane;
        float os = acc * 64.f;
        _Float16 h1 = (_Float16)os;
        o1[ob] = h1;
        o2[ob] = (_Float16)(os - (float)h1);
    }
}

// ---------------- MFMA flash attention S=400 (user BERT) ----------------
#define SSTR 449
__global__ __launch_bounds__(256) void attn_flash400(const float* __restrict__ Q,
    const float* __restrict__ Km, const float* __restrict__ V,
    const float* __restrict__ mask, _Float16* __restrict__ o1, _Float16* __restrict__ o2)
{
    __shared__ _Float16 Kt[64 * 64];
    __shared__ float Sc[16 * SSTR];
    int qt = blockIdx.x % 25;
    int h  = (blockIdx.x / 25) % NHEAD;
    int g  = blockIdx.x / (25 * NHEAD);
    int tid = threadIdx.x, w = tid >> 6, lane = tid & 63, lm = lane & 15, kg = lane >> 4;

    v8h aq0, aq1;
    {
        const float* qp = Q + ((size_t)(g * 400 + qt * 16 + lm)) * DIM + h * DHEAD;
#pragma unroll
        for (int u = 0; u < 8; u++) {
            aq0[u] = (_Float16)qp[kg * 8 + u];
            aq1[u] = (_Float16)qp[32 + kg * 8 + u];
        }
    }
    for (int jt = 0; jt < 7; jt++) {
        int j0 = jt * 64;
        __syncthreads();
        {
            int jr = tid >> 2, c0 = (tid & 3) << 4;
            int j = j0 + jr;
            _Float16* kd = Kt + jr * 64 + c0;
            if (j < 400) {
                const float* kp = Km + ((size_t)(g * 400 + j)) * DIM + h * DHEAD + c0;
#pragma unroll
                for (int u = 0; u < 16; u++) kd[u] = (_Float16)kp[u];
            } else {
#pragma unroll
                for (int u = 0; u < 16; u++) kd[u] = (_Float16)0.f;
            }
        }
        __syncthreads();
        v8h b0, b1;
#pragma unroll
        for (int u = 0; u < 8; u++) {
            b0[u] = Kt[(w * 16 + lm) * 64 + kg * 8 + u];
            b1[u] = Kt[(w * 16 + lm) * 64 + 32 + kg * 8 + u];
        }
        v4f c = {0.f, 0.f, 0.f, 0.f};
        c = __builtin_amdgcn_mfma_f32_16x16x32_f16(aq0, b0, c, 0, 0, 0);
        c = __builtin_amdgcn_mfma_f32_16x16x32_f16(aq1, b1, c, 0, 0, 0);
        int jj = j0 + w * 16 + lm;
        float mv = (jj < 400) ? (mask[g * 400 + jj] > 0.f ? 0.f : -1e9f) : -1e9f;
#pragma unroll
        for (int r = 0; r < 4; r++)
            Sc[(kg * 4 + r) * SSTR + jj] = c[r] * 0.125f + mv;
    }
    __syncthreads();
    for (int rr = 0; rr < 4; rr++) {
        int r = w * 4 + rr;
        float mx = -INFINITY;
#pragma unroll
        for (int c7 = 0; c7 < 7; c7++) mx = fmaxf(mx, Sc[r * SSTR + c7 * 64 + lane]);
#pragma unroll
        for (int o = 32; o; o >>= 1) mx = fmaxf(mx, __shfl_xor(mx, o));
        float s = 0.f;
        float ev[7];
#pragma unroll
        for (int c7 = 0; c7 < 7; c7++) { ev[c7] = expf(Sc[r * SSTR + c7 * 64 + lane] - mx); s += ev[c7]; }
#pragma unroll
        for (int o = 32; o; o >>= 1) s += __shfl_xor(s, o);
        float inv = 1.f / s;
#pragma unroll
        for (int c7 = 0; c7 < 7; c7++) Sc[r * SSTR + c7 * 64 + lane] = ev[c7] * inv;
    }
    __syncthreads();
    v4f o = {0.f, 0.f, 0.f, 0.f};
    for (int kc = 0; kc < 14; kc++) {
        v8h a, b;
#pragma unroll
        for (int u = 0; u < 8; u++) a[u] = (_Float16)Sc[lm * SSTR + kc * 32 + kg * 8 + u];
#pragma unroll
        for (int u = 0; u < 8; u++) {
            int j = kc * 32 + kg * 8 + u;
            b[u] = (j < 400) ? (_Float16)V[((size_t)(g * 400 + j)) * DIM + h * DHEAD + w * 16 + lm]
                             : (_Float16)0.f;
        }
        o = __builtin_amdgcn_mfma_f32_16x16x32_f16(a, b, o, 0, 0, 0);
    }
#pragma unroll
    for (int r = 0; r < 4; r++) {
        int qr = qt * 16 + kg * 4 + r;
        size_t ob = ((size_t)(g * 400 + qr)) * DIM + h * DHEAD + w * 16 + lm;
        float os = o[r] * 64.f;
        _Float16 h1 = (_Float16)os;
        o1[ob] = h1; o2[ob] = (_Float16)(os - (float)h1);
    }
}

// ---------------- LayerNorm(X + Y) with fused split / dual-out / cls ----------------
__global__ __launch_bounds__(256) void add_ln2(const float* __restrict__ X,
    const float* __restrict__ Y, float* __restrict__ outA, float* __restrict__ outB,
    int bndRow, _Float16* __restrict__ S1, _Float16* __restrict__ S2, float ss,
    float* __restrict__ cls, int clsOffA, int clsOffB, int S)
{
    int r = blockIdx.x, tid = threadIdx.x;
    size_t base = (size_t)r * DIM;
    float v0 = X[base + tid] + Y[base + tid];
    float v1 = X[base + tid + 256] + Y[base + tid + 256];
    float v2 = X[base + tid + 512] + Y[base + tid + 512];
    __shared__ float red[256];
    red[tid] = v0 + v1 + v2; __syncthreads();
    for (int o = 128; o; o >>= 1) { if (tid < o) red[tid] += red[tid + o]; __syncthreads(); }
    float mu = red[0] * (1.f / 768.f);
    __syncthreads();
    float d0 = v0 - mu, d1 = v1 - mu, d2 = v2 - mu;
    red[tid] = d0 * d0 + d1 * d1 + d2 * d2; __syncthreads();
    for (int o = 128; o; o >>= 1) { if (tid < o) red[tid] += red[tid + o]; __syncthreads(); }
    float rstd = rsqrtf(red[0] * (1.f / 768.f) + 1e-12f);
    float o0 = d0 * rstd, o1 = d1 * rstd, o2 = d2 * rstd;
    float* Out = (r < bndRow) ? outA + base : outB + (size_t)(r - bndRow) * DIM;
    Out[tid] = o0; Out[tid + 256] = o1; Out[tid + 512] = o2;
    if (S1) {
        float x0 = o0 * ss, x1 = o1 * ss, x2 = o2 * ss;
        _Float16 a0 = (_Float16)x0, a1 = (_Float16)x1, a2 = (_Float16)x2;
        S1[base + tid] = a0;        S2[base + tid] = (_Float16)(x0 - (float)a0);
        S1[base + tid + 256] = a1;  S2[base + tid + 256] = (_Float16)(x1 - (float)a1);
        S1[base + tid + 512] = a2;  S2[base + tid + 512] = (_Float16)(x2 - (float)a2);
    }
    if (cls && (r % S) == 0) {
        int g = (r < bndRow) ? clsOffA + r / S : clsOffB + (r - bndRow) / S;
        float* cd = cls + (size_t)g * DIM;
        cd[tid] = o0; cd[tid + 256] = o1; cd[tid + 512] = o2;
    }
}

// ---------------- legacy fp32 SIMT GEMM (tiny proj GEMMs only) ----------------
__global__ __launch_bounds__(256) void gemm_kernel(const float* __restrict__ A,
    const float* __restrict__ B, float* __restrict__ C,
    int M, int N, int Kd, int epi, const float* __restrict__ bias)
{
    __shared__ float As[16][64];
    __shared__ float Bs[16][64];
    int tid = threadIdx.x;
    int tx = tid & 15, ty = tid >> 4;
    int row0 = blockIdx.y << 6, col0 = blockIdx.x << 6;
    int ar = tid >> 2, ak = (tid & 3) << 2;
    int bc = tid & 63, bk0 = tid >> 6;
    const float* Ap = A + (size_t)(row0 + ar) * Kd + ak;
    const float* Bp = B + (size_t)bk0 * N + col0 + bc;
    bool aval = (row0 + ar) < M;
    float acc[4][4];
#pragma unroll
    for (int i = 0; i < 4; i++)
#pragma unroll
        for (int j = 0; j < 4; j++) acc[i][j] = 0.f;
    for (int k0 = 0; k0 < Kd; k0 += 16) {
        float4 a4 = make_float4(0.f, 0.f, 0.f, 0.f);
        if (aval) a4 = *(const float4*)(Ap + k0);
        As[ak + 0][ar] = a4.x; As[ak + 1][ar] = a4.y;
        As[ak + 2][ar] = a4.z; As[ak + 3][ar] = a4.w;
#pragma unroll
        for (int i = 0; i < 4; i++)
            Bs[bk0 + 4 * i][bc] = Bp[(size_t)(k0 + 4 * i) * N];
        __syncthreads();
#pragma unroll
        for (int kk = 0; kk < 16; kk++) {
            float4 av = *(const float4*)&As[kk][ty << 2];
            float4 bv = *(const float4*)&Bs[kk][tx << 2];
            float aa[4] = {av.x, av.y, av.z, av.w};
            float bb[4] = {bv.x, bv.y, bv.z, bv.w};
#pragma unroll
            for (int i = 0; i < 4; i++)
#pragma unroll
                for (int j = 0; j < 4; j++)
                    acc[i][j] = fmaf(aa[i], bb[j], acc[i][j]);
        }
        __syncthreads();
    }
#pragma unroll
    for (int i = 0; i < 4; i++) {
        int r = row0 + (ty << 2) + i;
        if (r >= M) continue;
        float v[4];
#pragma unroll
        for (int j = 0; j < 4; j++) {
            float x = acc[i][j];
            if (epi == 1) x = gelu_f(x);
            else if (epi == 2) x = tanhf(x + bias[col0 + (tx << 2) + j]);
            v[j] = x;
        }
        *(float4*)(C + (size_t)r * N + col0 + (tx << 2)) = make_float4(v[0], v[1], v[2], v[3]);
    }
}

// ---------------- user attention pooling (kept: exact order, feeds kid) -------------
__global__ __launch_bounds__(256) void user_pool_kernel(const float* __restrict__ cls,
    const float* __restrict__ qU, float* __restrict__ user0)
{
    int b = blockIdx.x, tid = threadIdx.x;
    __shared__ float red[256];
    __shared__ float wv[64];
    const float scale = 0.03608439182435161f;
    for (int n = 0; n < 50; n++) {
        const float* cr = cls + ((size_t)(b * 50 + n)) * DIM;
        float d = 0.f;
        for (int t = tid; t < DIM; t += 256) d = fmaf(cr[t], qU[t], d);
        red[tid] = d; __syncthreads();
        for (int o = 128; o; o >>= 1) { if (tid < o) red[tid] += red[tid + o]; __syncthreads(); }
        if (tid == 0) wv[n] = red[0] * scale;
        __syncthreads();
    }
    if (tid == 0) {
        float mx = -INFINITY;
        for (int n = 0; n < 50; n++) mx = fmaxf(mx, wv[n]);
        float s = 0.f;
        for (int n = 0; n < 50; n++) { float e = expf(wv[n] - mx); wv[n] = e; s += e; }
        float inv = 1.f / s;
        for (int n = 0; n < 50; n++) wv[n] *= inv;
    }
    __syncthreads();
    for (int d = tid; d < DIM; d += 256) {
        float a = 0.f;
        for (int n = 0; n < 50; n++) a = fmaf(wv[n], cls[((size_t)(b * 50 + n)) * DIM + d], a);
        user0[(size_t)b * DIM + d] = a;
    }
}

// ---------------- personalized-term scores + stable top-8 ----------------
__global__ __launch_bounds__(256) void topk_kernel(const float* __restrict__ hid,
    const float* __restrict__ user0, const float* __restrict__ attn,
    float* __restrict__ kid_f, int* __restrict__ kid_i, float* __restrict__ ps_mask)
{
    int bn = blockIdx.x;
    int b = bn / 50;
    int tid = threadIdx.x, lane = tid & 63, w = tid >> 6;
    __shared__ float sc[64];
    const float* u = user0 + (size_t)b * DIM;
    const float scale = 0.03608439182435161f;
    for (int s = w; s < 64; s += 4) {
        const float* hr = hid + ((size_t)bn * 64 + s) * DIM;
        float d = 0.f;
        for (int t = lane; t < DIM; t += 64) d = fmaf(hr[t], u[t], d);
#pragma unroll
        for (int o = 32; o; o >>= 1) d += __shfl_down(d, o);
        if (lane == 0) {
            float a = attn[(size_t)bn * 64 + s];
            sc[s] = (a > 0.f) ? d * scale : -1e9f;
        }
    }
    __syncthreads();
    if (tid == 0) {
        unsigned long long used = 0ull;
        for (int k = 0; k < 8; k++) {
            float best = -INFINITY; int bi = 0;
            for (int s = 0; s < 64; s++) {
                if ((used >> s) & 1ull) continue;
                if (sc[s] > best) { best = sc[s]; bi = s; }
            }
            used |= (1ull << bi);
            kid_i[bn * 8 + k] = bi;
            kid_f[bn * 8 + k] = (float)bi;
            ps_mask[bn * 8 + k] = attn[(size_t)bn * 64 + bi];
        }
    }
}

// ---------------- gather with fused x64 split ----------------
__global__ void gather2(const float* __restrict__ hid, const int* __restrict__ kid_i,
    float* __restrict__ X, _Float16* __restrict__ s1, _Float16* __restrict__ s2)
{
    int r = blockIdx.x, tid = threadIdx.x;
    int s = kid_i[r];
    int bn = r >> 3;
    const float* src = hid + ((size_t)bn * 64 + s) * DIM;
    size_t base = (size_t)r * DIM;
#pragma unroll
    for (int cci = 0; cci < 3; cci++) {
        int cc = tid + (cci << 8);
        float v = src[cc];
        X[base + cc] = v;
        float xs = v * 64.f;
        _Float16 a = (_Float16)xs;
        s1[base + cc] = a;
        s2[base + cc] = (_Float16)(xs - (float)a);
    }
}

__global__ __launch_bounds__(256) void final_kernel(const float* __restrict__ cdd_repr,
    const float* __restrict__ user_repr, float* __restrict__ out)
{
    int b = blockIdx.x, tid = threadIdx.x;
    __shared__ float red[256];
    __shared__ float sc[5];
    const float scale = 0.03608439182435161f;
    for (int c = 0; c < 5; c++) {
        const float* cr = cdd_repr + ((size_t)(b * 5 + c)) * DIM;
        const float* ur = user_repr + (size_t)b * DIM;
        float d = 0.f;
        for (int t = tid; t < DIM; t += 256) d = fmaf(cr[t], ur[t], d);
        red[tid] = d; __syncthreads();
        for (int o = 128; o; o >>= 1) { if (tid < o) red[tid] += red[tid + o]; __syncthreads(); }
        if (tid == 0) sc[c] = red[0] * scale;
        __syncthreads();
    }
    if (tid == 0) {
        float mx = -INFINITY;
        for (int c = 0; c < 5; c++) mx = fmaxf(mx, sc[c]);
        float s = 0.f;
        for (int c = 0; c < 5; c++) s += expf(sc[c] - mx);
        float lse = logf(s) + mx;
        for (int c = 0; c < 5; c++) out[b * 5 + c] = sc[c] - lse;
    }
}

extern "C" void kernel_launch(void* const* d_in, const int* in_sizes, int n_in,
                              void* d_out, int out_size, void* d_ws, size_t ws_size,
                              hipStream_t stream)
{
    (void)in_sizes; (void)n_in; (void)out_size;
    const int*   cdd_sub   = (const int*)d_in[0];
    const int*   his_sub   = (const int*)d_in[1];
    const int*   cdd_enc   = (const int*)d_in[2];
    const int*   his_enc   = (const int*)d_in[3];
    const float* cdd_mask  = (const float*)d_in[4];
    const float* his_mask  = (const float*)d_in[5];
    const float* cdd_amask = (const float*)d_in[6];
    const float* his_amask = (const float*)d_in[7];
    const float* emb = (const float*)d_in[8];
    const float* bWsrc[6] = {(const float*)d_in[9],  (const float*)d_in[10], (const float*)d_in[11],
                             (const float*)d_in[12], (const float*)d_in[13], (const float*)d_in[14]};
    const float* eWsrc[6] = {(const float*)d_in[15], (const float*)d_in[16], (const float*)d_in[17],
                             (const float*)d_in[18], (const float*)d_in[19], (const float*)d_in[20]};
    const float* qU = (const float*)d_in[21];
    const float* pW = (const float*)d_in[22];
    const float* pb = (const float*)d_in[23];
    float* out = (float*)d_out;

    // ---- workspace-fitted chunk schedule (ws_size is process-constant: graph-safe) ----
    auto al256 = [](size_t b) { return (b + 255) & ~(size_t)255; };
    auto needBytes = [&](size_t RCx) -> size_t {
        size_t t = 0;
        t += 4 * al256(RCx * 768 * 4);          // R_X, R_Q, R_K, R_V
        t += 2 * al256(RCx * 768 * 2);          // s1h, s2h
        t += al256(RCx * 3072 * 2);             // g2h (also cdd-discard scratch)
        t += al256((size_t)440 * 4096 * 4);     // Pa
        t += al256((size_t)400 * 64 * 768 * 4); // hisH
        t += al256((size_t)448 * 768 * 4);      // cls
        t += 8 * al256(131072);                  // small buffers (overestimate)
        t += 3 * (4 * al256((size_t)589824 * 2) + 2 * al256((size_t)2359296 * 2)); // weights
        return t;
    };
    // NS = history seqs per chunk (even -> all row counts multiple of 128).
    // Chunk 0 additionally carries the 40 cdd seqs (2560 rows, bert weights).
    const int NSopts[9] = {400, 200, 134, 100, 66, 50, 34, 24, 10};
    int NS = 10;
    for (int i = 0; i < 9; i++) {
        size_t RCt = (size_t)NSopts[i] * 64 + 2560;
        if (needBytes(RCt) <= ws_size) { NS = NSopts[i]; break; }
    }
    const size_t RC = (size_t)NS * 64 + 2560;

    // ---- workspace carve (order must match needBytes) ----
    char* wsb = (char*)d_ws;
    size_t off = 0;
    auto allocB = [&](size_t bytes) { char* p = wsb + off; off += al256(bytes); return p; };
    float* R_X = (float*)allocB(RC * 768 * 4);
    float* R_Q = (float*)allocB(RC * 768 * 4);
    float* R_K = (float*)allocB(RC * 768 * 4);   // g1h aliases K+V during FFN
    float* R_V = (float*)allocB(RC * 768 * 4);
    _Float16* s1h = (_Float16*)allocB(RC * 768 * 2);
    _Float16* s2h = (_Float16*)allocB(RC * 768 * 2);
    _Float16* g2h = (_Float16*)allocB(RC * 3072 * 2);
    float* Pa   = (float*)allocB((size_t)440 * 4096 * 4);
    float* hisH = (float*)allocB((size_t)400 * 64 * 768 * 4);
    float* cls  = (float*)allocB((size_t)448 * 768 * 4);   // g 0..399 his, 400..439 cdd
    float* userC = (float*)allocB(131072);
    float* hisA  = (float*)allocB(131072);
    float* cddA  = (float*)allocB(131072);
    float* cddR  = (float*)allocB(131072);
    float* userR = (float*)allocB(131072);
    float* user0 = (float*)allocB(131072);
    float* psM   = (float*)allocB(131072);
    int*   kidI  = (int*)allocB(131072);
    size_t wsz[6] = {589824, 589824, 589824, 589824, 2359296, 2359296};
    _Float16 *eB1s[6], *eB2s[6], *bB1s[6];
    for (int i = 0; i < 6; i++) eB1s[i] = (_Float16*)allocB(wsz[i] * 2);
    for (int i = 0; i < 6; i++) eB2s[i] = (_Float16*)allocB(wsz[i] * 2);
    for (int i = 0; i < 6; i++) bB1s[i] = (_Float16*)allocB(wsz[i] * 2);
    _Float16* g1h = (_Float16*)R_K;       // M*3072 halves over R_K+R_V (M <= RC)
    float* cddTrash = (float*)g2h;        // cdd hidden-state sink (never read; g2h dead then)

    // ---- single-launch coalesced weight transpose+split (x64) ----
    int wk[6] = {768, 768, 768, 768, 768, 3072};
    int wn[6] = {768, 768, 768, 768, 3072, 768};
    {
        WJobs jb{};
        int st = 0;
        for (int i = 0; i < 6; i++) {
            jb.src[i] = eWsrc[i]; jb.d1[i] = eB1s[i]; jb.d2[i] = eB2s[i];
            jb.K[i] = wk[i]; jb.N[i] = wn[i]; jb.start[i] = st;
            st += (wk[i] >> 5) * (wn[i] >> 5);
        }
        for (int i = 0; i < 6; i++) {
            jb.src[6 + i] = bWsrc[i]; jb.d1[6 + i] = bB1s[i]; jb.d2[6 + i] = nullptr;
            jb.K[6 + i] = wk[i]; jb.N[6 + i] = wn[i]; jb.start[6 + i] = st;
            st += (wk[i] >> 5) * (wn[i] >> 5);
        }
        wsplit_tr<<<st, 256, 0, stream>>>(jb);
    }

    // ---- prefix matrices + pooled attn masks for all 440 sequences ----
    build_prefix2<<<440, 256, 0, stream>>>(his_sub, his_mask, his_amask,
                                           cdd_sub, cdd_mask, cdd_amask, Pa, hisA, cddA);

    auto mkP = [&](int sl, int bnd) {
        GemmP g{};
        g.A1 = s1h; g.A2 = s2h;
        for (int z = 0; z < 3; z++) {
            g.eB1[z] = eB1s[sl]; g.eB2[z] = eB2s[sl]; g.bB1[z] = bB1s[sl];
        }
        g.bnd = bnd;
        return g;
    };

    // ---- one transformer pass (rows<bnd: encN nt=3; rows>=bnd: bert nt=1) ----
    auto tf = [&](int M, int bnd, int nseqTot, int gMid, const float* mHis,
                  float* outA, float* outB, float* clsArena, int clsOffA, int clsOffB,
                  int S, bool userAttn) {
        int MB = M >> 7;
        GemmP gq = mkP(0, bnd);
        for (int z = 0; z < 3; z++) { gq.eB1[z] = eB1s[z]; gq.eB2[z] = eB2s[z]; gq.bB1[z] = bB1s[z]; }
        gq.C[0] = R_Q; gq.C[1] = R_K; gq.C[2] = R_V;
        gemm_mfma<<<dim3(6, MB, 3), 256, 0, stream>>>(gq, M, 768, 768, 0, 1.f / 4096.f, 0.f);
        if (!userAttn) {
            attn_fused64<<<nseqTot * NHEAD, 256, 0, stream>>>(R_Q, R_K, R_V, mHis, cddA, gMid, s1h, s2h);
        } else {
            attn_flash400<<<8 * NHEAD * 25, 256, 0, stream>>>(R_Q, R_K, R_V, mHis, s1h, s2h);
        }
        GemmP go = mkP(3, bnd);
        go.C[0] = R_Q;
        gemm_mfma<<<dim3(6, MB, 1), 256, 0, stream>>>(go, M, 768, 768, 0, 1.f / 4096.f, 0.f);
        add_ln2<<<M, 256, 0, stream>>>(R_X, R_Q, R_X, R_X, M, s1h, s2h, 1.f, nullptr, 0, 0, 64);
        GemmP g1 = mkP(4, bnd);
        g1.G1 = g1h; g1.G2 = g2h;
        gemm_mfma<<<dim3(24, MB, 1), 256, 0, stream>>>(g1, M, 3072, 768, 1, 1.f / 64.f, 16.f);
        GemmP g2 = mkP(5, bnd);
        g2.A1 = g1h; g2.A2 = g2h; g2.C[0] = R_Q;
        gemm_mfma<<<dim3(6, MB, 1), 256, 0, stream>>>(g2, M, 768, 3072, 0, 1.f / 1024.f, 0.f);
        add_ln2<<<M, 256, 0, stream>>>(R_X, R_Q, outA, outB, bnd, nullptr, nullptr, 0.f,
                                       clsArena, clsOffA, clsOffB, S);
    };

    // ---- history (+cdd in first chunk) encoder, NS his seqs per chunk ----
    int done = 0;
    bool first = true;
    while (done < 400) {
        int ns = NS < (400 - done) ? NS : (400 - done);
        int hisRows = ns * 64;
        int M = hisRows + (first ? 2560 : 0);
        int nseqTot = ns + (first ? 40 : 0);
        emb_pool2<<<nseqTot * 4, 256, 0, stream>>>(Pa, his_enc, cdd_enc, emb, R_X, s1h, s2h, done, ns);
        tf(M, hisRows, nseqTot, ns, hisA + (size_t)done * 64,
           hisH + (size_t)done * 64 * DIM, cddTrash, cls, done, 400, 64, false);
        done += ns;
        first = false;
    }

    // ---- candidate projection from cls rows 400..439 ----
    gemm_kernel<<<dim3(12, 1), 256, 0, stream>>>(cls + (size_t)400 * 768, pW, cddR, 40, 768, 768, 2, pb);

    // ---- user encoder + matching reducer (fp32, exact order) ----
    user_pool_kernel<<<8, 256, 0, stream>>>(cls, qU, user0);
    topk_kernel<<<400, 256, 0, stream>>>(hisH, user0, hisA, out + 40, kidI, psM);
    gather2<<<3200, 256, 0, stream>>>(hisH, kidI, R_X, s1h, s2h);

    // ---- user BERT over 3200 selected terms (all bert: bnd=0; flash400 attn) ----
    tf(3200, 0, 8, 0, psM, hisH, hisH, userC, 0, 0, 400, true);
    gemm_kernel<<<dim3(12, 1), 256, 0, stream>>>(userC, pW, userR, 8, 768, 768, 2, pb);

    final_kernel<<<8, 256, 0, stream>>>(cddR, userR, out);
}